// Round 10
// baseline (3317.660 us; speedup 1.0000x reference)
//
#include <hip/hip_runtime.h>

typedef __attribute__((ext_vector_type(8))) short short8;
typedef __attribute__((ext_vector_type(4))) float f32x4;

__device__ __forceinline__ float4 ld4(const float* p){ return *reinterpret_cast<const float4*>(p); }
__device__ __forceinline__ void st4(float* p, const float4& v){ *reinterpret_cast<float4*>(p) = v; }

__device__ __forceinline__ unsigned short f2b(float x){
  unsigned int u = __float_as_uint(x);
  unsigned int r = (u + 0x7fffu + ((u >> 16) & 1u)) >> 16;
  return (unsigned short)r;
}
__device__ __forceinline__ float b2f(unsigned short b){
  return __uint_as_float(((unsigned int)b) << 16);
}

__device__ __forceinline__ float fsigmoid(float x){ return 1.f / (1.f + __expf(-x)); }
__device__ __forceinline__ float ftanh(float x){ return 1.f - 2.f / (1.f + __expf(2.f * x)); }

__device__ __forceinline__ short8 cvt_frag(float4 f0, float4 f1){
  short8 a;
  a[0]=(short)f2b(f0.x); a[1]=(short)f2b(f0.y); a[2]=(short)f2b(f0.z); a[3]=(short)f2b(f0.w);
  a[4]=(short)f2b(f1.x); a[5]=(short)f2b(f1.y); a[6]=(short)f2b(f1.z); a[7]=(short)f2b(f1.w);
  return a;
}

// ============ weight fragmentization ============
// k-major source: B[k][col] (ldb = cols). Layout: BF[((kb*CTG+ctg)*64+lane)*8+j]
__global__ void build_frag_kmajor(const float* __restrict__ B, int ldb,
                                  unsigned short* __restrict__ BF, int KB, int CTG)
{
  int idx = blockIdx.x * 256 + threadIdx.x;
  int total = KB * CTG * 512;
  if (idx >= total) return;
  int j = idx & 7, lane = (idx >> 3) & 63, rest = idx >> 9;
  int ctg = rest % CTG, kb = rest / CTG;
  int k = kb * 32 + ((lane >> 4) << 3) + j;
  int col = ctg * 16 + (lane & 15);
  BF[idx] = f2b(B[(size_t)k * ldb + col]);
}

// LSTM col-half layout for lstm_cell3:
// BF[((hf*8+kb)*16+ct)*512 + lane*8 + j], col = (ct>>2)*128 + hf*64 + (ct&3)*16 + (lane&15),
// k = kb*32 + ((lane>>4)<<3) + j ; k<128 -> Wih, else Whh (both [512][128] row-major)
__global__ void build_frag_lstm4(const float* __restrict__ Wih, const float* __restrict__ Whh,
                                 unsigned short* __restrict__ BF)
{
  int idx = blockIdx.x * 256 + threadIdx.x;
  if (idx >= 131072) return;
  int j = idx & 7, lane = (idx >> 3) & 63;
  int ct = (idx >> 9) & 15, kb = (idx >> 13) & 7, hf = idx >> 16;
  int col = (ct >> 2) * 128 + hf * 64 + (ct & 3) * 16 + (lane & 15);
  int k = kb * 32 + ((lane >> 4) << 3) + j;
  float v = (k < 128) ? Wih[(size_t)col * 128 + k] : Whh[(size_t)col * 128 + (k - 128)];
  BF[idx] = f2b(v);
}

// ============ generic MFMA GEMM: C[N x (CTG*16)] = A[N x KB*32] * B ============
template<int CT, int KB, int OUTBF, int RELU, int ABF16>
__global__ __launch_bounds__(256)
void gemm_mfma(const void* __restrict__ Av, int lda,
               const unsigned short* __restrict__ BF, int ctgTot,
               float* __restrict__ Cf, unsigned short* __restrict__ Cb, int ldc,
               const float* __restrict__ bias, int nrows)
{
  const int tid = threadIdx.x, lane = tid & 63, wid = tid >> 6;
  const int row0 = blockIdx.x * 64 + wid * 16;
  const int cg = blockIdx.y * CT;
  const int r = row0 + (lane & 15);
  const bool rok = r < nrows;
  const int koff = (lane >> 4) << 3;

  f32x4 acc[CT];
#pragma unroll
  for (int ct = 0; ct < CT; ++ct) {
    float b = bias ? bias[(cg + ct) * 16 + (lane & 15)] : 0.f;
    acc[ct] = (f32x4){b, b, b, b};
  }

#pragma unroll
  for (int kb = 0; kb < KB; ++kb) {
    short8 a = {};
    if (rok) {
      if (ABF16) {
        a = *(const short8*)((const unsigned short*)Av + (size_t)r * lda + kb * 32 + koff);
      } else {
        const float* p = (const float*)Av + (size_t)r * lda + kb * 32 + koff;
        a = cvt_frag(ld4(p), ld4(p + 4));
      }
    }
#pragma unroll
    for (int ct = 0; ct < CT; ++ct) {
      const short8 b = *(const short8*)(BF + ((size_t)(kb * ctgTot + cg + ct) * 64 + lane) * 8);
      acc[ct] = __builtin_amdgcn_mfma_f32_16x16x32_bf16(a, b, acc[ct], 0, 0, 0);
    }
  }

  const int orow = row0 + ((lane >> 4) << 2);
#pragma unroll
  for (int ct = 0; ct < CT; ++ct) {
    int col = (cg + ct) * 16 + (lane & 15);
#pragma unroll
    for (int rg = 0; rg < 4; ++rg) {
      int rr = orow + rg;
      if (rr >= nrows) continue;
      float v = acc[ct][rg];
      if (RELU) v = fmaxf(v, 0.f);
      if (OUTBF) Cb[(size_t)rr * ldc + col] = f2b(v);
      else       Cf[(size_t)rr * ldc + col] = v;
    }
  }
}

// ============ persistent LSTM cell (v7): weights staged in LDS ONCE, row-loop ============
// grid (G, 2): blockIdx.y = col-half hf (j in [hf*64, hf*64+64)). Block 512 thr (8 waves).
// Each block: stage 128 KB of weight frags -> LDS, then grid-stride over 128-row tiles.
// Per tile per wave: 16 rows x 256 gate-cols (16 col-tiles), acc 64 VGPR, fused pointwise.
template<int KBMAX>
__global__ __launch_bounds__(512, 2)
void lstm_cell3(const unsigned short* __restrict__ Ax, int ldx,
                const unsigned short* __restrict__ Ah, int ldh,
                const unsigned short* __restrict__ BF,
                const float* __restrict__ bi, const float* __restrict__ bh,
                const float* __restrict__ cin, float* __restrict__ cout,
                unsigned short* __restrict__ hb, int ldhb,
                float* __restrict__ hf32, int ldhf,
                float* __restrict__ hlast, int nrows)
{
  __shared__ unsigned short lb[65536];  // 128 KB: [8 kb][16 ct][64 lane][8]
  const int tid = threadIdx.x, lane = tid & 63, w = tid >> 6;  // w in 0..7
  const int hf_ = blockIdx.y;
  const int c15 = lane & 15, quad = lane >> 4;
  const int koff = quad << 3;
  const int G = gridDim.x;

  // ---- stage weights (once) ----
  const unsigned short* BFh = BF + (size_t)hf_ * 65536;
  for (int itc = 0; itc < 16; ++itc) {
    int chunk = w * 16 + itc;                       // 128 chunks x 1 KB
    const unsigned short* g = BFh + chunk * 512 + lane * 8;
    __builtin_amdgcn_global_load_lds((const __attribute__((address_space(1))) void*)g,
                                     (__attribute__((address_space(3))) void*)(&lb[chunk * 512]),
                                     16, 0, 0);
  }

  float bs[16];
#pragma unroll
  for (int ct = 0; ct < 16; ++ct) {
    int col = (ct >> 2) * 128 + hf_ * 64 + (ct & 3) * 16 + c15;
    bs[ct] = bi[col] + bh[col];
  }
  __syncthreads();  // weights resident

  const int T = (nrows + 127) >> 7;
  for (int tile = blockIdx.x; tile < T; tile += G) {
    const int r = tile * 128 + w * 16 + c15;
    const bool rok = r < nrows;

    f32x4 acc[16];
#pragma unroll
    for (int ct = 0; ct < 16; ++ct) acc[ct] = (f32x4){bs[ct], bs[ct], bs[ct], bs[ct]};

#pragma unroll
    for (int kb = 0; kb < KBMAX; ++kb) {
      short8 a = {};
      if (rok) {
        const unsigned short* ap = (kb < 4) ? (Ax + (size_t)r * ldx + kb * 32 + koff)
                                            : (Ah + (size_t)r * ldh + (kb - 4) * 32 + koff);
        a = *(const short8*)ap;
      }
#pragma unroll
      for (int ct = 0; ct < 16; ++ct) {
        const short8 b = *(const short8*)(lb + ((kb * 16 + ct) * 64 + lane) * 8);
        acc[ct] = __builtin_amdgcn_mfma_f32_16x16x32_bf16(a, b, acc[ct], 0, 0, 0);
      }
    }

    // fused pointwise; lane's output rows: orow..orow+3, cols j = hf*64 + q*16 + c15
    const int orow = tile * 128 + w * 16 + quad * 4;
#pragma unroll
    for (int q = 0; q < 4; ++q) {
      int j = hf_ * 64 + q * 16 + c15;
#pragma unroll
      for (int rg = 0; rg < 4; ++rg) {
        int rr = orow + rg;
        if (rr >= nrows) continue;
        float si = fsigmoid(acc[q][rg]);
        float sf = fsigmoid(acc[4 + q][rg]);
        float gg = ftanh(acc[8 + q][rg]);
        float so = fsigmoid(acc[12 + q][rg]);
        float cp = cin ? cin[(size_t)rr * 128 + j] : 0.f;
        float c = sf * cp + si * gg;
        cout[(size_t)rr * 128 + j] = c;
        float hh = so * ftanh(c);
        hb[(size_t)rr * ldhb + j] = f2b(hh);
        if (hf32)  hf32[(size_t)rr * ldhf + j] = hh;
        if (hlast) hlast[(size_t)rr * 128 + j] = hh;
      }
    }
  }
}

// ============ encoder tail: itype part + bias + relu + mask -> bf16 ============
__global__ void encoder_finish_kernel(const float* __restrict__ pre, const float* __restrict__ itype,
                                      const float* __restrict__ mask, const float* __restrict__ Wenc,
                                      const float* __restrict__ benc, unsigned short* __restrict__ hb, int n)
{
  int idx = blockIdx.x * blockDim.x + threadIdx.x;
  if (idx >= n * 128) return;
  int nn = idx >> 7, j = idx & 127;
  float v = pre[idx]
          + itype[nn * 3 + 0] * Wenc[128 * 128 + j]
          + itype[nn * 3 + 1] * Wenc[129 * 128 + j]
          + itype[nn * 3 + 2] * Wenc[130 * 128 + j]
          + benc[j];
  hb[idx] = f2b(fmaxf(v, 0.f) * mask[nn]);
}

// ============ CSR build ============
__global__ void count_kernel(const int* __restrict__ dst, int* __restrict__ cnt, int E, int EP)
{
  int e = blockIdx.x * blockDim.x + threadIdx.x;
  if (e >= EP) return;
  int d = (e < E) ? dst[e] : (e - E);
  atomicAdd(&cnt[d], 1);
}

__global__ void scan_kernel(const int* __restrict__ cnt, int* __restrict__ indptr, int n)
{
  __shared__ int wsum[16];
  int tid = threadIdx.x;
  int lane = tid & 63, wv = tid >> 6;
  int run = 0;
  for (int base = 0; base < n; base += 1024) {
    int idx = base + tid;
    int v = (idx < n) ? cnt[idx] : 0;
    int x = v;
#pragma unroll
    for (int off = 1; off < 64; off <<= 1) { int y = __shfl_up(x, off); if (lane >= off) x += y; }
    if (lane == 63) wsum[wv] = x;
    __syncthreads();
    if (wv == 0) {
      int t = (lane < 16) ? wsum[lane] : 0;
#pragma unroll
      for (int off = 1; off < 16; off <<= 1) { int y = __shfl_up(t, off); if (lane >= off) t += y; }
      if (lane < 16) wsum[lane] = t;
    }
    __syncthreads();
    int offs = wv ? wsum[wv - 1] : 0;
    int tot = wsum[15];
    if (idx < n) indptr[idx] = run + offs + x - v;
    run += tot;
    __syncthreads();
  }
  if (tid == 0) indptr[n] = run;
}

__global__ void fill_kernel(const int* __restrict__ src, const int* __restrict__ dst,
                            const int* __restrict__ indptr, int* __restrict__ fillc,
                            int* __restrict__ srcl, int E, int EP)
{
  int e = blockIdx.x * blockDim.x + threadIdx.x;
  if (e >= EP) return;
  int d, s;
  if (e < E) { d = dst[e]; s = src[e]; } else { d = e - E; s = e - E; }
  int pos = atomicAdd(&fillc[d], 1);
  srcl[indptr[d] + pos] = s;
}

// ============ GAT: per-node attention logits (bf16 xh) ============
__global__ void gat_att_kernel(const unsigned short* __restrict__ xhb,
                               const float* __restrict__ attS, const float* __restrict__ attD,
                               float* __restrict__ aS, float* __restrict__ aD, int n)
{
  int idx = blockIdx.x * blockDim.x + threadIdx.x;
  if (idx >= n * 4) return;
  int nn = idx >> 2, hd = idx & 3;
  const uint4* xr = (const uint4*)(xhb + (size_t)nn * 128 + hd * 32);
  const float* as_ = attS + hd * 32;
  const float* ad_ = attD + hd * 32;
  float s = 0.f, d = 0.f;
#pragma unroll
  for (int w = 0; w < 4; ++w) {
    uint4 v = xr[w];
    unsigned int u[4] = {v.x, v.y, v.z, v.w};
#pragma unroll
    for (int c = 0; c < 4; ++c) {
      float lo = b2f((unsigned short)(u[c] & 0xffff));
      float hi = b2f((unsigned short)(u[c] >> 16));
      int o = w * 8 + c * 2;
      s = fmaf(lo, as_[o], s);     d = fmaf(lo, ad_[o], d);
      s = fmaf(hi, as_[o + 1], s); d = fmaf(hi, ad_[o + 1], d);
    }
  }
  aS[idx] = s; aD[idx] = d;
}

// ============ GAT: stats + alpha (wave per dst) ============
__global__ __launch_bounds__(256)
void gat_stats_kernel(const float* __restrict__ aS, const float* __restrict__ aD,
                      const int* __restrict__ indptr, const int* __restrict__ srcl,
                      float* __restrict__ alpha4, int n)
{
  int wid = (int)((blockIdx.x * (size_t)blockDim.x + threadIdx.x) >> 6);
  int lane = threadIdx.x & 63;
  if (wid >= n) return;
  int eb = indptr[wid], ee = indptr[wid + 1];
  float4 ad = ld4(aD + wid * 4);
  float m0 = -3e38f, m1 = -3e38f, m2 = -3e38f, m3 = -3e38f;
  for (int i = eb + lane; i < ee; i += 64) {
    int s = srcl[i];
    float4 as = ld4(aS + s * 4);
    float e0 = as.x + ad.x; e0 = e0 > 0.f ? e0 : 0.2f * e0; m0 = fmaxf(m0, e0);
    float e1 = as.y + ad.y; e1 = e1 > 0.f ? e1 : 0.2f * e1; m1 = fmaxf(m1, e1);
    float e2 = as.z + ad.z; e2 = e2 > 0.f ? e2 : 0.2f * e2; m2 = fmaxf(m2, e2);
    float e3 = as.w + ad.w; e3 = e3 > 0.f ? e3 : 0.2f * e3; m3 = fmaxf(m3, e3);
  }
#pragma unroll
  for (int off = 32; off; off >>= 1) {
    m0 = fmaxf(m0, __shfl_xor(m0, off)); m1 = fmaxf(m1, __shfl_xor(m1, off));
    m2 = fmaxf(m2, __shfl_xor(m2, off)); m3 = fmaxf(m3, __shfl_xor(m3, off));
  }
  float s0 = 0.f, s1 = 0.f, s2 = 0.f, s3 = 0.f;
  for (int i = eb + lane; i < ee; i += 64) {
    int s = srcl[i];
    float4 as = ld4(aS + s * 4);
    float e0 = as.x + ad.x; e0 = e0 > 0.f ? e0 : 0.2f * e0; s0 += __expf(e0 - m0);
    float e1 = as.y + ad.y; e1 = e1 > 0.f ? e1 : 0.2f * e1; s1 += __expf(e1 - m1);
    float e2 = as.z + ad.z; e2 = e2 > 0.f ? e2 : 0.2f * e2; s2 += __expf(e2 - m2);
    float e3 = as.w + ad.w; e3 = e3 > 0.f ? e3 : 0.2f * e3; s3 += __expf(e3 - m3);
  }
#pragma unroll
  for (int off = 32; off; off >>= 1) {
    s0 += __shfl_xor(s0, off); s1 += __shfl_xor(s1, off);
    s2 += __shfl_xor(s2, off); s3 += __shfl_xor(s3, off);
  }
  float i0 = 1.f / (s0 + 1e-16f), i1 = 1.f / (s1 + 1e-16f);
  float i2 = 1.f / (s2 + 1e-16f), i3 = 1.f / (s3 + 1e-16f);
  for (int i = eb + lane; i < ee; i += 64) {
    int s = srcl[i];
    float4 as = ld4(aS + s * 4);
    float e0 = as.x + ad.x; e0 = e0 > 0.f ? e0 : 0.2f * e0;
    float e1 = as.y + ad.y; e1 = e1 > 0.f ? e1 : 0.2f * e1;
    float e2 = as.z + ad.z; e2 = e2 > 0.f ? e2 : 0.2f * e2;
    float e3 = as.w + ad.w; e3 = e3 > 0.f ? e3 : 0.2f * e3;
    float4 al = make_float4(__expf(e0 - m0) * i0, __expf(e1 - m1) * i1,
                            __expf(e2 - m2) * i2, __expf(e3 - m3) * i3);
    st4(alpha4 + (size_t)i * 4, al);
  }
}

// ============ GAT: slim weighted gather (wave per dst), bf16 store only ============
__global__ __launch_bounds__(256)
void gat_agg2_kernel(const unsigned short* __restrict__ xhb, const float* __restrict__ alpha4,
                     const int* __restrict__ indptr, const int* __restrict__ srcl,
                     const float* __restrict__ bgat, unsigned short* __restrict__ outb,
                     int ldo, int n)
{
  int wid = (int)((blockIdx.x * (size_t)blockDim.x + threadIdx.x) >> 6);
  int lane = threadIdx.x & 63;
  if (wid >= n) return;
  int eb = indptr[wid], ee = indptr[wid + 1];
  int hsel = lane >> 4;
  float acc0 = 0.f, acc1 = 0.f;
  for (int i = eb; i < ee; ++i) {
    int s = srcl[i];
    float4 a4 = ld4(alpha4 + (size_t)i * 4);
    float av = (hsel == 0) ? a4.x : (hsel == 1) ? a4.y : (hsel == 2) ? a4.z : a4.w;
    unsigned int px = *(const unsigned int*)(xhb + (size_t)s * 128 + lane * 2);
    acc0 = fmaf(av, b2f((unsigned short)(px & 0xffff)), acc0);
    acc1 = fmaf(av, b2f((unsigned short)(px >> 16)), acc1);
  }
  float ox = acc0 + bgat[lane * 2];
  float oy = acc1 + bgat[lane * 2 + 1];
  unsigned int pk = (unsigned int)f2b(ox) | ((unsigned int)f2b(oy) << 16);
  *reinterpret_cast<unsigned int*>(outb + (size_t)wid * ldo + lane * 2) = pk;
}

// ============ impact head layer 2 + |.| mean ============
__global__ __launch_bounds__(256)
void impact_out_kernel(const float* __restrict__ hid, const float* __restrict__ W2,
                       const float* __restrict__ b2, float* __restrict__ outp,
                       float* __restrict__ total, float wk, int n)
{
  __shared__ float red[256];
  int idx = blockIdx.x * 256 + threadIdx.x;
  float part = 0.f;
  if (idx < n) {
    const float* h = hid + (size_t)idx * 64;
    float o0 = b2[0], o1 = b2[1], o2 = b2[2];
#pragma unroll 8
    for (int k = 0; k < 64; ++k) {
      float v = h[k];
      o0 = fmaf(v, W2[k * 3 + 0], o0);
      o1 = fmaf(v, W2[k * 3 + 1], o1);
      o2 = fmaf(v, W2[k * 3 + 2], o2);
    }
    outp[(size_t)idx * 3 + 0] = o0;
    outp[(size_t)idx * 3 + 1] = o1;
    outp[(size_t)idx * 3 + 2] = o2;
    part = fabsf(o0) + fabsf(o1) + fabsf(o2);
  }
  red[threadIdx.x] = part;
  __syncthreads();
  for (int s = 128; s; s >>= 1) {
    if (threadIdx.x < s) red[threadIdx.x] += red[threadIdx.x + s];
    __syncthreads();
  }
  if (threadIdx.x == 0) atomicAdd(total, red[0] * wk);
}

// ============ host ============
extern "C" void kernel_launch(void* const* d_in, const int* in_sizes, int n_in,
                              void* d_out, int out_size, void* d_ws, size_t ws_size,
                              hipStream_t stream)
{
  const float* x     = (const float*)d_in[0];
  const int*   ei    = (const int*)  d_in[1];
  const float* mask  = (const float*)d_in[2];
  const float* itype = (const float*)d_in[3];
  const float* Wenc  = (const float*)d_in[4];
  const float* benc  = (const float*)d_in[5];
  const float* Wgat  = (const float*)d_in[6];
  const float* attS  = (const float*)d_in[7];
  const float* attD  = (const float*)d_in[8];
  const float* bgat  = (const float*)d_in[9];
  const float* W1    = (const float*)d_in[10];
  const float* b1    = (const float*)d_in[11];
  const float* W2    = (const float*)d_in[12];
  const float* b2    = (const float*)d_in[13];
  const float* Wih0  = (const float*)d_in[14];
  const float* Whh0  = (const float*)d_in[15];
  const float* bih0  = (const float*)d_in[16];
  const float* bhh0  = (const float*)d_in[17];
  const float* Wih1  = (const float*)d_in[18];
  const float* Whh1  = (const float*)d_in[19];
  const float* bih1  = (const float*)d_in[20];
  const float* bhh1  = (const float*)d_in[21];

  const int N  = in_sizes[0] / 128;
  const int E  = in_sizes[1] / 2;
  const int EP = E + N;

  float* out      = (float*)d_out;
  float* impacts  = out;
  float* temporal = out + (size_t)3 * N * 3;     // [N][3][128], ld 384
  float* hlast    = temporal + (size_t)N * 384;  // [N][128]
  float* total    = hlast + (size_t)N * 128;

  // ---- workspace layout ----
  float* ws = (float*)d_ws;
  float* c0 = ws;                                 // N*128 f (encoder scratch / aS,aD / L0 c)
  float* c1 = c0 + (size_t)N * 128;               // N*128 f (alpha4 / imp hidden / L1 c)
  unsigned short* tempb = (unsigned short*)(c1 + (size_t)N * 128);  // [N][3][128] bf16
  unsigned short* hb0   = tempb + (size_t)N * 384;                  // N*128 bf16 (enc out)
  unsigned short* xhb   = hb0 + (size_t)N * 128;                    // N*128 bf16 (xh)
  int* indptr = (int*)(xhb + (size_t)N * 128);    // N+1
  int* fillc  = indptr + (N + 1);                 // N
  int* srcl   = fillc + N;                        // EP
  size_t ip = (size_t)((srcl + EP) - (int*)ws);
  ip = (ip + 7) & ~(size_t)7;
  unsigned short* frags = (unsigned short*)((int*)ws + ip);
  unsigned short* WencF = frags;                  // 16384
  unsigned short* WgatF = WencF + 16384;          // 3*16384
  unsigned short* W1F   = WgatF + 3 * 16384;      // 3*8192
  unsigned short* L0F   = W1F + 3 * 8192;         // 131072
  unsigned short* L1F   = L0F + 131072;           // 131072

  float* regA   = c1;
  float* alpha4 = c1;
  float* aS     = c0;
  float* aD     = c0 + (size_t)N * 4;

  size_t need = ((size_t)N * 128 * 2) * 4 + (size_t)N * 384 * 2 + (size_t)N * 128 * 2 * 2
              + ((size_t)2 * N + 1 + EP + 8) * 4 + (size_t)(16384 * 4 + 8192 * 3 + 131072 * 2) * 2 + 64;
  if (ws_size < need) return;

  const int* esrc = ei;
  const int* edst = ei + E;
  const int rowTiles = (N + 63) / 64;

  // ---- build weight fragments ----
  build_frag_kmajor<<<64, 256, 0, stream>>>(Wenc, 128, WencF, 4, 8);
  for (int k = 0; k < 3; ++k) {
    build_frag_kmajor<<<64, 256, 0, stream>>>(Wgat + (size_t)k * 16384, 128, WgatF + (size_t)k * 16384, 4, 8);
    build_frag_kmajor<<<32, 256, 0, stream>>>(W1 + (size_t)k * 8192, 64, W1F + (size_t)k * 8192, 4, 4);
  }
  build_frag_lstm4<<<512, 256, 0, stream>>>(Wih0, Whh0, L0F);
  build_frag_lstm4<<<512, 256, 0, stream>>>(Wih1, Whh1, L1F);

  // ---- CSR by destination (self-loops appended) ----
  hipMemsetAsync(fillc, 0, (size_t)N * sizeof(int), stream);
  count_kernel<<<(EP + 255) / 256, 256, 0, stream>>>(edst, fillc, E, EP);
  scan_kernel<<<1, 1024, 0, stream>>>(fillc, indptr, N);
  hipMemsetAsync(fillc, 0, (size_t)N * sizeof(int), stream);
  fill_kernel<<<(EP + 255) / 256, 256, 0, stream>>>(esrc, edst, indptr, fillc, srcl, E, EP);

  // ---- encoder ----
  gemm_mfma<8, 4, 0, 0, 0><<<dim3(rowTiles, 1), 256, 0, stream>>>(
      x, 128, WencF, 8, c0, nullptr, 128, nullptr, N);
  encoder_finish_kernel<<<(N * 128 + 255) / 256, 256, 0, stream>>>(c0, itype, mask, Wenc, benc, hb0, N);

  hipMemsetAsync(total, 0, sizeof(float), stream);

  const int waveGrid = (N * 64 + 255) / 256;

  // ---- 3 GAT hops + impact heads ----
  for (int k = 0; k < 3; ++k) {
    const unsigned short* hinb = (k == 0) ? hb0 : (tempb + (size_t)(k - 1) * 128);
    int ldin = (k == 0) ? 128 : 384;
    gemm_mfma<8, 4, 1, 0, 1><<<dim3(rowTiles, 1), 256, 0, stream>>>(
        hinb, ldin, WgatF + (size_t)k * 16384, 8, nullptr, xhb, 128, nullptr, N);
    gat_att_kernel<<<(N * 4 + 255) / 256, 256, 0, stream>>>(xhb, attS + k * 128, attD + k * 128, aS, aD, N);
    gat_stats_kernel<<<waveGrid, 256, 0, stream>>>(aS, aD, indptr, srcl, alpha4, N);
    gat_agg2_kernel<<<waveGrid, 256, 0, stream>>>(xhb, alpha4, indptr, srcl, bgat + k * 128,
                                                  tempb + (size_t)k * 128, 384, N);
    gemm_mfma<4, 4, 0, 1, 1><<<dim3(rowTiles, 1), 256, 0, stream>>>(
        tempb + (size_t)k * 128, 384, W1F + (size_t)k * 8192, 4,
        regA, nullptr, 64, b1 + k * 64, N);
    float wk = ((k == 0) ? 1.f : (k == 1) ? 0.5f : 0.25f) / (3.0f * (float)N);
    impact_out_kernel<<<(N + 255) / 256, 256, 0, stream>>>(regA, W2 + k * 192, b2 + k * 3,
                                                           impacts + (size_t)k * N * 3, total, wk, N);
  }

  // ---- LSTM: 6 persistent cell dispatches (weights in LDS, row-loop) ----
  unsigned short* hl0[2] = {hb0, xhb};  // ping-pong layer-0 h (free after GAT)
  const dim3 lgrid(128, 2);
  for (int t = 0; t < 3; ++t) {
    // layer 0: A = [tempb[t] | h0_prev], c = c0, out h0 bf16
    if (t == 0)
      lstm_cell3<4><<<lgrid, 512, 0, stream>>>(
          tempb + (size_t)t * 128, 384, nullptr, 128, L0F, bih0, bhh0,
          nullptr, c0, hl0[0], 128, nullptr, 0, nullptr, N);
    else
      lstm_cell3<8><<<lgrid, 512, 0, stream>>>(
          tempb + (size_t)t * 128, 384, hl0[(t - 1) & 1], 128, L0F, bih0, bhh0,
          c0, c0, hl0[t & 1], 128, nullptr, 0, nullptr, N);
    // layer 1: A = [h0_t | h1_prev(tempb[t-1])], c = c1, out h1 -> tempb[t] bf16 + temporal fp32
    if (t == 0)
      lstm_cell3<4><<<lgrid, 512, 0, stream>>>(
          hl0[0], 128, nullptr, 384, L1F, bih1, bhh1,
          nullptr, c1, tempb + (size_t)0, 384, temporal + (size_t)0, 384, nullptr, N);
    else
      lstm_cell3<8><<<lgrid, 512, 0, stream>>>(
          hl0[t & 1], 128, tempb + (size_t)(t - 1) * 128, 384, L1F, bih1, bhh1,
          c1, c1, tempb + (size_t)t * 128, 384, temporal + (size_t)t * 128, 384,
          (t == 2 ? hlast : nullptr), N);
  }
}

// Round 11
// 2059.253 us; speedup vs baseline: 1.6111x; 1.6111x over previous
//
#include <hip/hip_runtime.h>

typedef __attribute__((ext_vector_type(8))) short short8;
typedef __attribute__((ext_vector_type(4))) float f32x4;

__device__ __forceinline__ float4 ld4(const float* p){ return *reinterpret_cast<const float4*>(p); }
__device__ __forceinline__ void st4(float* p, const float4& v){ *reinterpret_cast<float4*>(p) = v; }

__device__ __forceinline__ unsigned short f2b(float x){
  unsigned int u = __float_as_uint(x);
  unsigned int r = (u + 0x7fffu + ((u >> 16) & 1u)) >> 16;
  return (unsigned short)r;
}
__device__ __forceinline__ float b2f(unsigned short b){
  return __uint_as_float(((unsigned int)b) << 16);
}

__device__ __forceinline__ float fsigmoid(float x){ return 1.f / (1.f + __expf(-x)); }
__device__ __forceinline__ float ftanh(float x){ return 1.f - 2.f / (1.f + __expf(2.f * x)); }

__device__ __forceinline__ short8 cvt_frag(float4 f0, float4 f1){
  short8 a;
  a[0]=(short)f2b(f0.x); a[1]=(short)f2b(f0.y); a[2]=(short)f2b(f0.z); a[3]=(short)f2b(f0.w);
  a[4]=(short)f2b(f1.x); a[5]=(short)f2b(f1.y); a[6]=(short)f2b(f1.z); a[7]=(short)f2b(f1.w);
  return a;
}

// ============ weight fragmentization ============
// k-major source: B[k][col] (ldb = cols). Layout: BF[((kb*CTG+ctg)*64+lane)*8+j]
__global__ void build_frag_kmajor(const float* __restrict__ B, int ldb,
                                  unsigned short* __restrict__ BF, int KB, int CTG)
{
  int idx = blockIdx.x * 256 + threadIdx.x;
  int total = KB * CTG * 512;
  if (idx >= total) return;
  int j = idx & 7, lane = (idx >> 3) & 63, rest = idx >> 9;
  int ctg = rest % CTG, kb = rest / CTG;
  int k = kb * 32 + ((lane >> 4) << 3) + j;
  int col = ctg * 16 + (lane & 15);
  BF[idx] = f2b(B[(size_t)k * ldb + col]);
}

// LSTM wave-slice layout (8 waves x 16 j-cols each) — round-5 layout:
// BF[(((w*8+kb)*4+g)*64+lane)*8+j], col = g*128 + w*16 + (lane&15),
// k = kb*32 + ((lane>>4)<<3) + j ; k<128 -> Wih, else Whh
__global__ void build_frag_lstm3(const float* __restrict__ Wih, const float* __restrict__ Whh,
                                 unsigned short* __restrict__ BF)
{
  int idx = blockIdx.x * 256 + threadIdx.x;
  if (idx >= 131072) return;
  int j = idx & 7, lane = (idx >> 3) & 63;
  int g = (idx >> 9) & 3, kb = (idx >> 11) & 7, w = idx >> 14;
  int col = g * 128 + w * 16 + (lane & 15);
  int k = kb * 32 + ((lane >> 4) << 3) + j;
  float v = (k < 128) ? Wih[(size_t)col * 128 + k] : Whh[(size_t)col * 128 + (k - 128)];
  BF[idx] = f2b(v);
}

// ============ generic MFMA GEMM ============
template<int CT, int KB, int OUTBF, int RELU, int ABF16>
__global__ __launch_bounds__(256)
void gemm_mfma(const void* __restrict__ Av, int lda,
               const unsigned short* __restrict__ BF, int ctgTot,
               float* __restrict__ Cf, unsigned short* __restrict__ Cb, int ldc,
               const float* __restrict__ bias, int nrows)
{
  const int tid = threadIdx.x, lane = tid & 63, wid = tid >> 6;
  const int row0 = blockIdx.x * 64 + wid * 16;
  const int cg = blockIdx.y * CT;
  const int r = row0 + (lane & 15);
  const bool rok = r < nrows;
  const int koff = (lane >> 4) << 3;

  f32x4 acc[CT];
#pragma unroll
  for (int ct = 0; ct < CT; ++ct) {
    float b = bias ? bias[(cg + ct) * 16 + (lane & 15)] : 0.f;
    acc[ct] = (f32x4){b, b, b, b};
  }

#pragma unroll
  for (int kb = 0; kb < KB; ++kb) {
    short8 a = {};
    if (rok) {
      if (ABF16) {
        a = *(const short8*)((const unsigned short*)Av + (size_t)r * lda + kb * 32 + koff);
      } else {
        const float* p = (const float*)Av + (size_t)r * lda + kb * 32 + koff;
        a = cvt_frag(ld4(p), ld4(p + 4));
      }
    }
#pragma unroll
    for (int ct = 0; ct < CT; ++ct) {
      const short8 b = *(const short8*)(BF + ((size_t)(kb * ctgTot + cg + ct) * 64 + lane) * 8);
      acc[ct] = __builtin_amdgcn_mfma_f32_16x16x32_bf16(a, b, acc[ct], 0, 0, 0);
    }
  }

  const int orow = row0 + ((lane >> 4) << 2);
#pragma unroll
  for (int ct = 0; ct < CT; ++ct) {
    int col = (cg + ct) * 16 + (lane & 15);
#pragma unroll
    for (int rg = 0; rg < 4; ++rg) {
      int rr = orow + rg;
      if (rr >= nrows) continue;
      float v = acc[ct][rg];
      if (RELU) v = fmaxf(v, 0.f);
      if (OUTBF) Cb[(size_t)rr * ldc + col] = f2b(v);
      else       Cf[(size_t)rr * ldc + col] = v;
    }
  }
}

// ============ fully fused 2-layer x T=3 LSTM (round-5 v2: 64-row, 8 waves, 16-j/wave) ============
__global__ __launch_bounds__(512, 2)
void lstm_fused(const unsigned short* __restrict__ tempb,  // [N][3][128] bf16 (GAT hops)
                const unsigned short* __restrict__ L0F, const unsigned short* __restrict__ L1F,
                const float* __restrict__ bih0, const float* __restrict__ bhh0,
                const float* __restrict__ bih1, const float* __restrict__ bhh1,
                float* __restrict__ temporal, float* __restrict__ hlast, int nrows)
{
  __shared__ unsigned short h0b[8192];  // [64][128] swizzled (elem ^= (row&7)<<3)
  __shared__ unsigned short h1b[8192];
  const int tid = threadIdx.x, lane = tid & 63, w = tid >> 6;  // w in 0..7
  const int row0 = blockIdx.x * 64;
  const int rbase = lane & 15;
  const int koff = (lane >> 4) << 3;
  const int c15 = lane & 15;
  const int jw = w * 16;

  float bs0[4], bs1[4];
#pragma unroll
  for (int g = 0; g < 4; ++g) {
    int col = g * 128 + jw + c15;
    bs0[g] = bih0[col] + bhh0[col];
    bs1[g] = bih1[col] + bhh1[col];
  }

  f32x4 c0[4], c1[4];
#pragma unroll
  for (int i = 0; i < 4; ++i) { c0[i] = (f32x4){0,0,0,0}; c1[i] = (f32x4){0,0,0,0}; }

  const unsigned short* BF0 = L0F + (size_t)w * 16384;
  const unsigned short* BF1 = L1F + (size_t)w * 16384;

  f32x4 acc[4][4];

  for (int t = 0; t < 3; ++t) {
    // ---------- layer 0 ----------
#pragma unroll
    for (int rf = 0; rf < 4; ++rf)
#pragma unroll
      for (int g = 0; g < 4; ++g) acc[rf][g] = (f32x4){bs0[g], bs0[g], bs0[g], bs0[g]};

#pragma unroll
    for (int kb = 0; kb < 4; ++kb) {
      short8 a[4];
#pragma unroll
      for (int rf = 0; rf < 4; ++rf) {
        int r = row0 + rf * 16 + rbase;
        a[rf] = (r < nrows) ? *(const short8*)(tempb + (size_t)r * 384 + t * 128 + kb * 32 + koff)
                            : (short8){0,0,0,0,0,0,0,0};
      }
#pragma unroll
      for (int g = 0; g < 4; ++g) {
        const short8 b = *(const short8*)(BF0 + (((size_t)kb * 4 + g) * 64 + lane) * 8);
#pragma unroll
        for (int rf = 0; rf < 4; ++rf)
          acc[rf][g] = __builtin_amdgcn_mfma_f32_16x16x32_bf16(a[rf], b, acc[rf][g], 0, 0, 0);
      }
    }
    if (t > 0) {
#pragma unroll
      for (int kb = 4; kb < 8; ++kb) {
        short8 a[4];
#pragma unroll
        for (int rf = 0; rf < 4; ++rf) {
          int rl = rf * 16 + rbase;
          int kk = (kb - 4) * 32 + koff;
          a[rf] = *(const short8*)(h0b + rl * 128 + (kk ^ ((rl & 7) << 3)));
        }
#pragma unroll
        for (int g = 0; g < 4; ++g) {
          const short8 b = *(const short8*)(BF0 + (((size_t)kb * 4 + g) * 64 + lane) * 8);
#pragma unroll
          for (int rf = 0; rf < 4; ++rf)
            acc[rf][g] = __builtin_amdgcn_mfma_f32_16x16x32_bf16(a[rf], b, acc[rf][g], 0, 0, 0);
        }
      }
    }

    __syncthreads();  // A

#pragma unroll
    for (int rf = 0; rf < 4; ++rf) {
      int j = jw + c15;
#pragma unroll
      for (int rg = 0; rg < 4; ++rg) {
        float si = fsigmoid(acc[rf][0][rg]);
        float sf = fsigmoid(acc[rf][1][rg]);
        float gg = ftanh(acc[rf][2][rg]);
        float so = fsigmoid(acc[rf][3][rg]);
        float c = sf * c0[rf][rg] + si * gg;
        c0[rf][rg] = c;
        float hh = so * ftanh(c);
        int rl = rf * 16 + ((lane >> 4) << 2) + rg;
        h0b[rl * 128 + (j ^ ((rl & 7) << 3))] = f2b(hh);
      }
    }

    __syncthreads();  // B

    // ---------- layer 1 ----------
#pragma unroll
    for (int rf = 0; rf < 4; ++rf)
#pragma unroll
      for (int g = 0; g < 4; ++g) acc[rf][g] = (f32x4){bs1[g], bs1[g], bs1[g], bs1[g]};

#pragma unroll
    for (int kb = 0; kb < 4; ++kb) {
      short8 a[4];
#pragma unroll
      for (int rf = 0; rf < 4; ++rf) {
        int rl = rf * 16 + rbase;
        int kk = kb * 32 + koff;
        a[rf] = *(const short8*)(h0b + rl * 128 + (kk ^ ((rl & 7) << 3)));
      }
#pragma unroll
      for (int g = 0; g < 4; ++g) {
        const short8 b = *(const short8*)(BF1 + (((size_t)kb * 4 + g) * 64 + lane) * 8);
#pragma unroll
        for (int rf = 0; rf < 4; ++rf)
          acc[rf][g] = __builtin_amdgcn_mfma_f32_16x16x32_bf16(a[rf], b, acc[rf][g], 0, 0, 0);
      }
    }
    if (t > 0) {
#pragma unroll
      for (int kb = 4; kb < 8; ++kb) {
        short8 a[4];
#pragma unroll
        for (int rf = 0; rf < 4; ++rf) {
          int rl = rf * 16 + rbase;
          int kk = (kb - 4) * 32 + koff;
          a[rf] = *(const short8*)(h1b + rl * 128 + (kk ^ ((rl & 7) << 3)));
        }
#pragma unroll
        for (int g = 0; g < 4; ++g) {
          const short8 b = *(const short8*)(BF1 + (((size_t)kb * 4 + g) * 64 + lane) * 8);
#pragma unroll
          for (int rf = 0; rf < 4; ++rf)
            acc[rf][g] = __builtin_amdgcn_mfma_f32_16x16x32_bf16(a[rf], b, acc[rf][g], 0, 0, 0);
        }
      }
    }

    __syncthreads();  // C

#pragma unroll
    for (int rf = 0; rf < 4; ++rf) {
      int j = jw + c15;
#pragma unroll
      for (int rg = 0; rg < 4; ++rg) {
        float si = fsigmoid(acc[rf][0][rg]);
        float sf = fsigmoid(acc[rf][1][rg]);
        float gg = ftanh(acc[rf][2][rg]);
        float so = fsigmoid(acc[rf][3][rg]);
        float c = sf * c1[rf][rg] + si * gg;
        c1[rf][rg] = c;
        float hh = so * ftanh(c);
        int rl = rf * 16 + ((lane >> 4) << 2) + rg;
        h1b[rl * 128 + (j ^ ((rl & 7) << 3))] = f2b(hh);
        int r = row0 + rl;
        if (r < nrows) {
          __builtin_nontemporal_store(hh, &temporal[(size_t)r * 384 + t * 128 + j]);
          if (t == 2) __builtin_nontemporal_store(hh, &hlast[(size_t)r * 128 + j]);
        }
      }
    }
  }
}

// ============ encoder tail ============
__global__ void encoder_finish_kernel(const float* __restrict__ pre, const float* __restrict__ itype,
                                      const float* __restrict__ mask, const float* __restrict__ Wenc,
                                      const float* __restrict__ benc, unsigned short* __restrict__ hb, int n)
{
  int idx = blockIdx.x * blockDim.x + threadIdx.x;
  if (idx >= n * 128) return;
  int nn = idx >> 7, j = idx & 127;
  float v = pre[idx]
          + itype[nn * 3 + 0] * Wenc[128 * 128 + j]
          + itype[nn * 3 + 1] * Wenc[129 * 128 + j]
          + itype[nn * 3 + 2] * Wenc[130 * 128 + j]
          + benc[j];
  hb[idx] = f2b(fmaxf(v, 0.f) * mask[nn]);
}

// ============ CSR build ============
__global__ void count_kernel(const int* __restrict__ dst, int* __restrict__ cnt, int E, int EP)
{
  int e = blockIdx.x * blockDim.x + threadIdx.x;
  if (e >= EP) return;
  int d = (e < E) ? dst[e] : (e - E);
  atomicAdd(&cnt[d], 1);
}

__global__ void scan_kernel(const int* __restrict__ cnt, int* __restrict__ indptr, int n)
{
  __shared__ int wsum[16];
  int tid = threadIdx.x;
  int lane = tid & 63, wv = tid >> 6;
  int run = 0;
  for (int base = 0; base < n; base += 1024) {
    int idx = base + tid;
    int v = (idx < n) ? cnt[idx] : 0;
    int x = v;
#pragma unroll
    for (int off = 1; off < 64; off <<= 1) { int y = __shfl_up(x, off); if (lane >= off) x += y; }
    if (lane == 63) wsum[wv] = x;
    __syncthreads();
    if (wv == 0) {
      int t = (lane < 16) ? wsum[lane] : 0;
#pragma unroll
      for (int off = 1; off < 16; off <<= 1) { int y = __shfl_up(t, off); if (lane >= off) t += y; }
      if (lane < 16) wsum[lane] = t;
    }
    __syncthreads();
    int offs = wv ? wsum[wv - 1] : 0;
    int tot = wsum[15];
    if (idx < n) indptr[idx] = run + offs + x - v;
    run += tot;
    __syncthreads();
  }
  if (tid == 0) indptr[n] = run;
}

__global__ void fill_kernel(const int* __restrict__ src, const int* __restrict__ dst,
                            const int* __restrict__ indptr, int* __restrict__ fillc,
                            int* __restrict__ srcl, int E, int EP)
{
  int e = blockIdx.x * blockDim.x + threadIdx.x;
  if (e >= EP) return;
  int d, s;
  if (e < E) { d = dst[e]; s = src[e]; } else { d = e - E; s = e - E; }
  int pos = atomicAdd(&fillc[d], 1);
  srcl[indptr[d] + pos] = s;
}

// ============ GAT: per-node attention logits (bf16 xh) ============
__global__ void gat_att_kernel(const unsigned short* __restrict__ xhb,
                               const float* __restrict__ attS, const float* __restrict__ attD,
                               float* __restrict__ aS, float* __restrict__ aD, int n)
{
  int idx = blockIdx.x * blockDim.x + threadIdx.x;
  if (idx >= n * 4) return;
  int nn = idx >> 2, hd = idx & 3;
  const uint4* xr = (const uint4*)(xhb + (size_t)nn * 128 + hd * 32);
  const float* as_ = attS + hd * 32;
  const float* ad_ = attD + hd * 32;
  float s = 0.f, d = 0.f;
#pragma unroll
  for (int w = 0; w < 4; ++w) {
    uint4 v = xr[w];
    unsigned int u[4] = {v.x, v.y, v.z, v.w};
#pragma unroll
    for (int c = 0; c < 4; ++c) {
      float lo = b2f((unsigned short)(u[c] & 0xffff));
      float hi = b2f((unsigned short)(u[c] >> 16));
      int o = w * 8 + c * 2;
      s = fmaf(lo, as_[o], s);     d = fmaf(lo, ad_[o], d);
      s = fmaf(hi, as_[o + 1], s); d = fmaf(hi, ad_[o + 1], d);
    }
  }
  aS[idx] = s; aD[idx] = d;
}

// ============ GAT: 2-pass stats — unnormalized alpha + reciprocal denominators ============
__global__ __launch_bounds__(256)
void gat_stats_kernel(const float* __restrict__ aS, const float* __restrict__ aD,
                      const int* __restrict__ indptr, const int* __restrict__ srcl,
                      float* __restrict__ alpha4, float* __restrict__ dinv4, int n)
{
  int wid = (int)((blockIdx.x * (size_t)blockDim.x + threadIdx.x) >> 6);
  int lane = threadIdx.x & 63;
  if (wid >= n) return;
  int eb = indptr[wid], ee = indptr[wid + 1];
  float4 ad = ld4(aD + wid * 4);
  // pass A: per-head max
  float m0 = -3e38f, m1 = -3e38f, m2 = -3e38f, m3 = -3e38f;
  for (int i = eb + lane; i < ee; i += 64) {
    int s = srcl[i];
    float4 as = ld4(aS + s * 4);
    float e0 = as.x + ad.x; e0 = e0 > 0.f ? e0 : 0.2f * e0; m0 = fmaxf(m0, e0);
    float e1 = as.y + ad.y; e1 = e1 > 0.f ? e1 : 0.2f * e1; m1 = fmaxf(m1, e1);
    float e2 = as.z + ad.z; e2 = e2 > 0.f ? e2 : 0.2f * e2; m2 = fmaxf(m2, e2);
    float e3 = as.w + ad.w; e3 = e3 > 0.f ? e3 : 0.2f * e3; m3 = fmaxf(m3, e3);
  }
#pragma unroll
  for (int off = 32; off; off >>= 1) {
    m0 = fmaxf(m0, __shfl_xor(m0, off)); m1 = fmaxf(m1, __shfl_xor(m1, off));
    m2 = fmaxf(m2, __shfl_xor(m2, off)); m3 = fmaxf(m3, __shfl_xor(m3, off));
  }
  // pass B: p = exp(e-m) stored unnormalized; accumulate sums
  float s0 = 0.f, s1 = 0.f, s2 = 0.f, s3 = 0.f;
  for (int i = eb + lane; i < ee; i += 64) {
    int s = srcl[i];
    float4 as = ld4(aS + s * 4);
    float e0 = as.x + ad.x; e0 = e0 > 0.f ? e0 : 0.2f * e0; float p0 = __expf(e0 - m0);
    float e1 = as.y + ad.y; e1 = e1 > 0.f ? e1 : 0.2f * e1; float p1 = __expf(e1 - m1);
    float e2 = as.z + ad.z; e2 = e2 > 0.f ? e2 : 0.2f * e2; float p2 = __expf(e2 - m2);
    float e3 = as.w + ad.w; e3 = e3 > 0.f ? e3 : 0.2f * e3; float p3 = __expf(e3 - m3);
    s0 += p0; s1 += p1; s2 += p2; s3 += p3;
    st4(alpha4 + (size_t)i * 4, make_float4(p0, p1, p2, p3));
  }
#pragma unroll
  for (int off = 32; off; off >>= 1) {
    s0 += __shfl_xor(s0, off); s1 += __shfl_xor(s1, off);
    s2 += __shfl_xor(s2, off); s3 += __shfl_xor(s3, off);
  }
  if (lane == 0) {
    st4(dinv4 + (size_t)wid * 4,
        make_float4(1.f / (s0 + 1e-16f), 1.f / (s1 + 1e-16f),
                    1.f / (s2 + 1e-16f), 1.f / (s3 + 1e-16f)));
  }
}

// ============ GAT: weighted gather; normalize by dinv in epilogue ============
__global__ __launch_bounds__(256)
void gat_agg2_kernel(const unsigned short* __restrict__ xhb, const float* __restrict__ alpha4,
                     const float* __restrict__ dinv4, const int* __restrict__ indptr,
                     const int* __restrict__ srcl, const float* __restrict__ bgat,
                     unsigned short* __restrict__ outb, int ldo, int n)
{
  int wid = (int)((blockIdx.x * (size_t)blockDim.x + threadIdx.x) >> 6);
  int lane = threadIdx.x & 63;
  if (wid >= n) return;
  int eb = indptr[wid], ee = indptr[wid + 1];
  int hsel = lane >> 4;
  float acc0 = 0.f, acc1 = 0.f;
  for (int i = eb; i < ee; ++i) {
    int s = srcl[i];
    float4 a4 = ld4(alpha4 + (size_t)i * 4);
    float av = (hsel == 0) ? a4.x : (hsel == 1) ? a4.y : (hsel == 2) ? a4.z : a4.w;
    unsigned int px = *(const unsigned int*)(xhb + (size_t)s * 128 + lane * 2);
    acc0 = fmaf(av, b2f((unsigned short)(px & 0xffff)), acc0);
    acc1 = fmaf(av, b2f((unsigned short)(px >> 16)), acc1);
  }
  float4 dv4 = ld4(dinv4 + (size_t)wid * 4);
  float dv = (hsel == 0) ? dv4.x : (hsel == 1) ? dv4.y : (hsel == 2) ? dv4.z : dv4.w;
  float ox = acc0 * dv + bgat[lane * 2];
  float oy = acc1 * dv + bgat[lane * 2 + 1];
  unsigned int pk = (unsigned int)f2b(ox) | ((unsigned int)f2b(oy) << 16);
  *reinterpret_cast<unsigned int*>(outb + (size_t)wid * ldo + lane * 2) = pk;
}

// ============ impact head layer 2 + |.| mean ============
__global__ __launch_bounds__(256)
void impact_out_kernel(const float* __restrict__ hid, const float* __restrict__ W2,
                       const float* __restrict__ b2, float* __restrict__ outp,
                       float* __restrict__ total, float wk, int n)
{
  __shared__ float red[256];
  int idx = blockIdx.x * 256 + threadIdx.x;
  float part = 0.f;
  if (idx < n) {
    const float* h = hid + (size_t)idx * 64;
    float o0 = b2[0], o1 = b2[1], o2 = b2[2];
#pragma unroll 8
    for (int k = 0; k < 64; ++k) {
      float v = h[k];
      o0 = fmaf(v, W2[k * 3 + 0], o0);
      o1 = fmaf(v, W2[k * 3 + 1], o1);
      o2 = fmaf(v, W2[k * 3 + 2], o2);
    }
    outp[(size_t)idx * 3 + 0] = o0;
    outp[(size_t)idx * 3 + 1] = o1;
    outp[(size_t)idx * 3 + 2] = o2;
    part = fabsf(o0) + fabsf(o1) + fabsf(o2);
  }
  red[threadIdx.x] = part;
  __syncthreads();
  for (int s = 128; s; s >>= 1) {
    if (threadIdx.x < s) red[threadIdx.x] += red[threadIdx.x + s];
    __syncthreads();
  }
  if (threadIdx.x == 0) atomicAdd(total, red[0] * wk);
}

// ============ host ============
extern "C" void kernel_launch(void* const* d_in, const int* in_sizes, int n_in,
                              void* d_out, int out_size, void* d_ws, size_t ws_size,
                              hipStream_t stream)
{
  const float* x     = (const float*)d_in[0];
  const int*   ei    = (const int*)  d_in[1];
  const float* mask  = (const float*)d_in[2];
  const float* itype = (const float*)d_in[3];
  const float* Wenc  = (const float*)d_in[4];
  const float* benc  = (const float*)d_in[5];
  const float* Wgat  = (const float*)d_in[6];
  const float* attS  = (const float*)d_in[7];
  const float* attD  = (const float*)d_in[8];
  const float* bgat  = (const float*)d_in[9];
  const float* W1    = (const float*)d_in[10];
  const float* b1    = (const float*)d_in[11];
  const float* W2    = (const float*)d_in[12];
  const float* b2    = (const float*)d_in[13];
  const float* Wih0  = (const float*)d_in[14];
  const float* Whh0  = (const float*)d_in[15];
  const float* bih0  = (const float*)d_in[16];
  const float* bhh0  = (const float*)d_in[17];
  const float* Wih1  = (const float*)d_in[18];
  const float* Whh1  = (const float*)d_in[19];
  const float* bih1  = (const float*)d_in[20];
  const float* bhh1  = (const float*)d_in[21];

  const int N  = in_sizes[0] / 128;
  const int E  = in_sizes[1] / 2;
  const int EP = E + N;

  float* out      = (float*)d_out;
  float* impacts  = out;
  float* temporal = out + (size_t)3 * N * 3;     // [N][3][128], ld 384
  float* hlast    = temporal + (size_t)N * 384;  // [N][128]
  float* total    = hlast + (size_t)N * 128;

  // ---- workspace layout ----
  float* ws = (float*)d_ws;
  float* c0 = ws;                                 // N*128 f (encoder scratch, then aS/aD/dinv)
  float* c1 = c0 + (size_t)N * 128;               // N*128 f (alpha4 / impact hidden)
  unsigned short* tempb = (unsigned short*)(c1 + (size_t)N * 128);  // [N][3][128] bf16
  unsigned short* hb0   = tempb + (size_t)N * 384;                  // N*128 bf16 (enc out)
  unsigned short* xhb   = hb0 + (size_t)N * 128;                    // N*128 bf16 (xh)
  int* indptr = (int*)(xhb + (size_t)N * 128);    // N+1
  int* fillc  = indptr + (N + 1);                 // N
  int* srcl   = fillc + N;                        // EP
  size_t ip = (size_t)((srcl + EP) - (int*)ws);
  ip = (ip + 7) & ~(size_t)7;
  unsigned short* frags = (unsigned short*)((int*)ws + ip);
  unsigned short* WencF = frags;                  // 16384
  unsigned short* WgatF = WencF + 16384;          // 3*16384
  unsigned short* W1F   = WgatF + 3 * 16384;      // 3*8192
  unsigned short* L0F   = W1F + 3 * 8192;         // 131072
  unsigned short* L1F   = L0F + 131072;           // 131072

  float* regA   = c1;
  float* alpha4 = c1;
  float* aS     = c0;
  float* aD     = c0 + (size_t)N * 4;
  float* dinv4  = c0 + (size_t)N * 8;

  size_t need = ((size_t)N * 128 * 2) * 4 + (size_t)N * 384 * 2 + (size_t)N * 128 * 2 * 2
              + ((size_t)2 * N + 1 + EP + 8) * 4 + (size_t)(16384 * 4 + 8192 * 3 + 131072 * 2) * 2 + 64;
  if (ws_size < need) return;

  const int* esrc = ei;
  const int* edst = ei + E;
  const int rowTiles = (N + 63) / 64;

  // ---- build weight fragments ----
  build_frag_kmajor<<<64, 256, 0, stream>>>(Wenc, 128, WencF, 4, 8);
  for (int k = 0; k < 3; ++k) {
    build_frag_kmajor<<<64, 256, 0, stream>>>(Wgat + (size_t)k * 16384, 128, WgatF + (size_t)k * 16384, 4, 8);
    build_frag_kmajor<<<32, 256, 0, stream>>>(W1 + (size_t)k * 8192, 64, W1F + (size_t)k * 8192, 4, 4);
  }
  build_frag_lstm3<<<512, 256, 0, stream>>>(Wih0, Whh0, L0F);
  build_frag_lstm3<<<512, 256, 0, stream>>>(Wih1, Whh1, L1F);

  // ---- CSR by destination (self-loops appended) ----
  hipMemsetAsync(fillc, 0, (size_t)N * sizeof(int), stream);
  count_kernel<<<(EP + 255) / 256, 256, 0, stream>>>(edst, fillc, E, EP);
  scan_kernel<<<1, 1024, 0, stream>>>(fillc, indptr, N);
  hipMemsetAsync(fillc, 0, (size_t)N * sizeof(int), stream);
  fill_kernel<<<(EP + 255) / 256, 256, 0, stream>>>(esrc, edst, indptr, fillc, srcl, E, EP);

  // ---- encoder ----
  gemm_mfma<8, 4, 0, 0, 0><<<dim3(rowTiles, 1), 256, 0, stream>>>(
      x, 128, WencF, 8, c0, nullptr, 128, nullptr, N);
  encoder_finish_kernel<<<(N * 128 + 255) / 256, 256, 0, stream>>>(c0, itype, mask, Wenc, benc, hb0, N);

  hipMemsetAsync(total, 0, sizeof(float), stream);

  const int waveGrid = (N * 64 + 255) / 256;

  // ---- 3 GAT hops + impact heads ----
  for (int k = 0; k < 3; ++k) {
    const unsigned short* hinb = (k == 0) ? hb0 : (tempb + (size_t)(k - 1) * 128);
    int ldin = (k == 0) ? 128 : 384;
    gemm_mfma<8, 4, 1, 0, 1><<<dim3(rowTiles, 1), 256, 0, stream>>>(
        hinb, ldin, WgatF + (size_t)k * 16384, 8, nullptr, xhb, 128, nullptr, N);
    gat_att_kernel<<<(N * 4 + 255) / 256, 256, 0, stream>>>(xhb, attS + k * 128, attD + k * 128, aS, aD, N);
    gat_stats_kernel<<<waveGrid, 256, 0, stream>>>(aS, aD, indptr, srcl, alpha4, dinv4, N);
    gat_agg2_kernel<<<waveGrid, 256, 0, stream>>>(xhb, alpha4, dinv4, indptr, srcl, bgat + k * 128,
                                                  tempb + (size_t)k * 128, 384, N);
    gemm_mfma<4, 4, 0, 1, 1><<<dim3(rowTiles, 1), 256, 0, stream>>>(
        tempb + (size_t)k * 128, 384, W1F + (size_t)k * 8192, 4,
        regA, nullptr, 64, b1 + k * 64, N);
    float wk = ((k == 0) ? 1.f : (k == 1) ? 0.5f : 0.25f) / (3.0f * (float)N);
    impact_out_kernel<<<(N + 255) / 256, 256, 0, stream>>>(regA, W2 + k * 192, b2 + k * 3,
                                                           impacts + (size_t)k * N * 3, total, wk, N);
  }

  // ---- fully fused LSTM (round-5 v2, best measured) ----
  lstm_fused<<<rowTiles, 512, 0, stream>>>(tempb, L0F, L1F, bih0, bhh0, bih1, bhh1,
                                           temporal, hlast, N);
}

// Round 12
// 1975.232 us; speedup vs baseline: 1.6796x; 1.0425x over previous
//
#include <hip/hip_runtime.h>

typedef __attribute__((ext_vector_type(8))) short short8;
typedef __attribute__((ext_vector_type(4))) float f32x4;

__device__ __forceinline__ float4 ld4(const float* p){ return *reinterpret_cast<const float4*>(p); }
__device__ __forceinline__ void st4(float* p, const float4& v){ *reinterpret_cast<float4*>(p) = v; }

__device__ __forceinline__ unsigned short f2b(float x){
  unsigned int u = __float_as_uint(x);
  unsigned int r = (u + 0x7fffu + ((u >> 16) & 1u)) >> 16;
  return (unsigned short)r;
}
__device__ __forceinline__ float b2f(unsigned short b){
  return __uint_as_float(((unsigned int)b) << 16);
}

__device__ __forceinline__ float fsigmoid(float x){ return 1.f / (1.f + __expf(-x)); }
__device__ __forceinline__ float ftanh(float x){ return 1.f - 2.f / (1.f + __expf(2.f * x)); }

__device__ __forceinline__ short8 cvt_frag(float4 f0, float4 f1){
  short8 a;
  a[0]=(short)f2b(f0.x); a[1]=(short)f2b(f0.y); a[2]=(short)f2b(f0.z); a[3]=(short)f2b(f0.w);
  a[4]=(short)f2b(f1.x); a[5]=(short)f2b(f1.y); a[6]=(short)f2b(f1.z); a[7]=(short)f2b(f1.w);
  return a;
}

// ============ weight fragmentization ============
__global__ void build_frag_kmajor(const float* __restrict__ B, int ldb,
                                  unsigned short* __restrict__ BF, int KB, int CTG)
{
  int idx = blockIdx.x * 256 + threadIdx.x;
  int total = KB * CTG * 512;
  if (idx >= total) return;
  int j = idx & 7, lane = (idx >> 3) & 63, rest = idx >> 9;
  int ctg = rest % CTG, kb = rest / CTG;
  int k = kb * 32 + ((lane >> 4) << 3) + j;
  int col = ctg * 16 + (lane & 15);
  BF[idx] = f2b(B[(size_t)k * ldb + col]);
}

// LSTM wave-slice layout (8 waves x 16 j-cols each), round-5 layout
__global__ void build_frag_lstm3(const float* __restrict__ Wih, const float* __restrict__ Whh,
                                 unsigned short* __restrict__ BF)
{
  int idx = blockIdx.x * 256 + threadIdx.x;
  if (idx >= 131072) return;
  int j = idx & 7, lane = (idx >> 3) & 63;
  int g = (idx >> 9) & 3, kb = (idx >> 11) & 7, w = idx >> 14;
  int col = g * 128 + w * 16 + (lane & 15);
  int k = kb * 32 + ((lane >> 4) << 3) + j;
  float v = (k < 128) ? Wih[(size_t)col * 128 + k] : Whh[(size_t)col * 128 + (k - 128)];
  BF[idx] = f2b(v);
}

// ============ generic MFMA GEMM ============
template<int CT, int KB, int OUTBF, int RELU, int ABF16>
__global__ __launch_bounds__(256)
void gemm_mfma(const void* __restrict__ Av, int lda,
               const unsigned short* __restrict__ BF, int ctgTot,
               float* __restrict__ Cf, unsigned short* __restrict__ Cb, int ldc,
               const float* __restrict__ bias, int nrows)
{
  const int tid = threadIdx.x, lane = tid & 63, wid = tid >> 6;
  const int row0 = blockIdx.x * 64 + wid * 16;
  const int cg = blockIdx.y * CT;
  const int r = row0 + (lane & 15);
  const bool rok = r < nrows;
  const int koff = (lane >> 4) << 3;

  f32x4 acc[CT];
#pragma unroll
  for (int ct = 0; ct < CT; ++ct) {
    float b = bias ? bias[(cg + ct) * 16 + (lane & 15)] : 0.f;
    acc[ct] = (f32x4){b, b, b, b};
  }

#pragma unroll
  for (int kb = 0; kb < KB; ++kb) {
    short8 a = {};
    if (rok) {
      if (ABF16) {
        a = *(const short8*)((const unsigned short*)Av + (size_t)r * lda + kb * 32 + koff);
      } else {
        const float* p = (const float*)Av + (size_t)r * lda + kb * 32 + koff;
        a = cvt_frag(ld4(p), ld4(p + 4));
      }
    }
#pragma unroll
    for (int ct = 0; ct < CT; ++ct) {
      const short8 b = *(const short8*)(BF + ((size_t)(kb * ctgTot + cg + ct) * 64 + lane) * 8);
      acc[ct] = __builtin_amdgcn_mfma_f32_16x16x32_bf16(a, b, acc[ct], 0, 0, 0);
    }
  }

  const int orow = row0 + ((lane >> 4) << 2);
#pragma unroll
  for (int ct = 0; ct < CT; ++ct) {
    int col = (cg + ct) * 16 + (lane & 15);
#pragma unroll
    for (int rg = 0; rg < 4; ++rg) {
      int rr = orow + rg;
      if (rr >= nrows) continue;
      float v = acc[ct][rg];
      if (RELU) v = fmaxf(v, 0.f);
      if (OUTBF) Cb[(size_t)rr * ldc + col] = f2b(v);
      else       Cf[(size_t)rr * ldc + col] = v;
    }
  }
}

// ============ fully fused 2-layer x T=3 LSTM (r5 structure + coalesced epilogue) ============
__global__ __launch_bounds__(512, 2)
void lstm_fused(const unsigned short* __restrict__ tempb,  // [N][3][128] bf16 (GAT hops)
                const unsigned short* __restrict__ L0F, const unsigned short* __restrict__ L1F,
                const float* __restrict__ bih0, const float* __restrict__ bhh0,
                const float* __restrict__ bih1, const float* __restrict__ bhh1,
                float* __restrict__ temporal, float* __restrict__ hlast, int nrows)
{
  __shared__ unsigned short h0b[8192];  // [64][128] swizzled (elem ^= (row&7)<<3)
  __shared__ unsigned short h1b[8192];
  __shared__ float h1f[64 * 132];       // fp32 staging tile (+4 pad per row)
  const int tid = threadIdx.x, lane = tid & 63, w = tid >> 6;  // w in 0..7
  const int row0 = blockIdx.x * 64;
  const int rbase = lane & 15;
  const int koff = (lane >> 4) << 3;
  const int c15 = lane & 15;
  const int jw = w * 16;

  float bs0[4], bs1[4];
#pragma unroll
  for (int g = 0; g < 4; ++g) {
    int col = g * 128 + jw + c15;
    bs0[g] = bih0[col] + bhh0[col];
    bs1[g] = bih1[col] + bhh1[col];
  }

  f32x4 c0[4], c1[4];
#pragma unroll
  for (int i = 0; i < 4; ++i) { c0[i] = (f32x4){0,0,0,0}; c1[i] = (f32x4){0,0,0,0}; }

  const unsigned short* BF0 = L0F + (size_t)w * 16384;
  const unsigned short* BF1 = L1F + (size_t)w * 16384;

  f32x4 acc[4][4];

  for (int t = 0; t < 3; ++t) {
    // ---------- layer 0 ----------
#pragma unroll
    for (int rf = 0; rf < 4; ++rf)
#pragma unroll
      for (int g = 0; g < 4; ++g) acc[rf][g] = (f32x4){bs0[g], bs0[g], bs0[g], bs0[g]};

#pragma unroll
    for (int kb = 0; kb < 4; ++kb) {
      short8 a[4];
#pragma unroll
      for (int rf = 0; rf < 4; ++rf) {
        int r = row0 + rf * 16 + rbase;
        a[rf] = (r < nrows) ? *(const short8*)(tempb + (size_t)r * 384 + t * 128 + kb * 32 + koff)
                            : (short8){0,0,0,0,0,0,0,0};
      }
#pragma unroll
      for (int g = 0; g < 4; ++g) {
        const short8 b = *(const short8*)(BF0 + (((size_t)kb * 4 + g) * 64 + lane) * 8);
#pragma unroll
        for (int rf = 0; rf < 4; ++rf)
          acc[rf][g] = __builtin_amdgcn_mfma_f32_16x16x32_bf16(a[rf], b, acc[rf][g], 0, 0, 0);
      }
    }
    if (t > 0) {
#pragma unroll
      for (int kb = 4; kb < 8; ++kb) {
        short8 a[4];
#pragma unroll
        for (int rf = 0; rf < 4; ++rf) {
          int rl = rf * 16 + rbase;
          int kk = (kb - 4) * 32 + koff;
          a[rf] = *(const short8*)(h0b + rl * 128 + (kk ^ ((rl & 7) << 3)));
        }
#pragma unroll
        for (int g = 0; g < 4; ++g) {
          const short8 b = *(const short8*)(BF0 + (((size_t)kb * 4 + g) * 64 + lane) * 8);
#pragma unroll
          for (int rf = 0; rf < 4; ++rf)
            acc[rf][g] = __builtin_amdgcn_mfma_f32_16x16x32_bf16(a[rf], b, acc[rf][g], 0, 0, 0);
        }
      }
    }

    __syncthreads();  // A

#pragma unroll
    for (int rf = 0; rf < 4; ++rf) {
      int j = jw + c15;
#pragma unroll
      for (int rg = 0; rg < 4; ++rg) {
        float si = fsigmoid(acc[rf][0][rg]);
        float sf = fsigmoid(acc[rf][1][rg]);
        float gg = ftanh(acc[rf][2][rg]);
        float so = fsigmoid(acc[rf][3][rg]);
        float c = sf * c0[rf][rg] + si * gg;
        c0[rf][rg] = c;
        float hh = so * ftanh(c);
        int rl = rf * 16 + ((lane >> 4) << 2) + rg;
        h0b[rl * 128 + (j ^ ((rl & 7) << 3))] = f2b(hh);
      }
    }

    __syncthreads();  // B

    // ---------- layer 1 ----------
#pragma unroll
    for (int rf = 0; rf < 4; ++rf)
#pragma unroll
      for (int g = 0; g < 4; ++g) acc[rf][g] = (f32x4){bs1[g], bs1[g], bs1[g], bs1[g]};

#pragma unroll
    for (int kb = 0; kb < 4; ++kb) {
      short8 a[4];
#pragma unroll
      for (int rf = 0; rf < 4; ++rf) {
        int rl = rf * 16 + rbase;
        int kk = kb * 32 + koff;
        a[rf] = *(const short8*)(h0b + rl * 128 + (kk ^ ((rl & 7) << 3)));
      }
#pragma unroll
      for (int g = 0; g < 4; ++g) {
        const short8 b = *(const short8*)(BF1 + (((size_t)kb * 4 + g) * 64 + lane) * 8);
#pragma unroll
        for (int rf = 0; rf < 4; ++rf)
          acc[rf][g] = __builtin_amdgcn_mfma_f32_16x16x32_bf16(a[rf], b, acc[rf][g], 0, 0, 0);
      }
    }
    if (t > 0) {
#pragma unroll
      for (int kb = 4; kb < 8; ++kb) {
        short8 a[4];
#pragma unroll
        for (int rf = 0; rf < 4; ++rf) {
          int rl = rf * 16 + rbase;
          int kk = (kb - 4) * 32 + koff;
          a[rf] = *(const short8*)(h1b + rl * 128 + (kk ^ ((rl & 7) << 3)));
        }
#pragma unroll
        for (int g = 0; g < 4; ++g) {
          const short8 b = *(const short8*)(BF1 + (((size_t)kb * 4 + g) * 64 + lane) * 8);
#pragma unroll
          for (int rf = 0; rf < 4; ++rf)
            acc[rf][g] = __builtin_amdgcn_mfma_f32_16x16x32_bf16(a[rf], b, acc[rf][g], 0, 0, 0);
        }
      }
    }

    __syncthreads();  // C

    // pointwise layer 1 -> h1b (bf16) + h1f (fp32 staging)
#pragma unroll
    for (int rf = 0; rf < 4; ++rf) {
      int j = jw + c15;
#pragma unroll
      for (int rg = 0; rg < 4; ++rg) {
        float si = fsigmoid(acc[rf][0][rg]);
        float sf = fsigmoid(acc[rf][1][rg]);
        float gg = ftanh(acc[rf][2][rg]);
        float so = fsigmoid(acc[rf][3][rg]);
        float c = sf * c1[rf][rg] + si * gg;
        c1[rf][rg] = c;
        float hh = so * ftanh(c);
        int rl = rf * 16 + ((lane >> 4) << 2) + rg;
        h1b[rl * 128 + (j ^ ((rl & 7) << 3))] = f2b(hh);
        h1f[rl * 132 + j] = hh;
      }
    }

    __syncthreads();  // D: staging tile complete

    // coalesced copy-out: half-wave writes a full 512B row-slice
#pragma unroll
    for (int k = 0; k < 4; ++k) {
      int idx = tid + k * 512;          // float4 index, 2048 total
      int row = idx >> 5;               // 64 rows x 32 float4
      int c4 = (idx & 31) << 2;
      int r = row0 + row;
      if (r < nrows) {
        float4 v = ld4(&h1f[row * 132 + c4]);
        st4(&temporal[(size_t)r * 384 + t * 128 + c4], v);
        if (t == 2) st4(&hlast[(size_t)r * 128 + c4], v);
      }
    }
  }
}

// ============ encoder tail ============
__global__ void encoder_finish_kernel(const float* __restrict__ pre, const float* __restrict__ itype,
                                      const float* __restrict__ mask, const float* __restrict__ Wenc,
                                      const float* __restrict__ benc, unsigned short* __restrict__ hb, int n)
{
  int idx = blockIdx.x * blockDim.x + threadIdx.x;
  if (idx >= n * 128) return;
  int nn = idx >> 7, j = idx & 127;
  float v = pre[idx]
          + itype[nn * 3 + 0] * Wenc[128 * 128 + j]
          + itype[nn * 3 + 1] * Wenc[129 * 128 + j]
          + itype[nn * 3 + 2] * Wenc[130 * 128 + j]
          + benc[j];
  hb[idx] = f2b(fmaxf(v, 0.f) * mask[nn]);
}

// ============ CSR build ============
__global__ void count_kernel(const int* __restrict__ dst, int* __restrict__ cnt, int E, int EP)
{
  int e = blockIdx.x * blockDim.x + threadIdx.x;
  if (e >= EP) return;
  int d = (e < E) ? dst[e] : (e - E);
  atomicAdd(&cnt[d], 1);
}

__global__ void scan_kernel(const int* __restrict__ cnt, int* __restrict__ indptr, int n)
{
  __shared__ int wsum[16];
  int tid = threadIdx.x;
  int lane = tid & 63, wv = tid >> 6;
  int run = 0;
  for (int base = 0; base < n; base += 1024) {
    int idx = base + tid;
    int v = (idx < n) ? cnt[idx] : 0;
    int x = v;
#pragma unroll
    for (int off = 1; off < 64; off <<= 1) { int y = __shfl_up(x, off); if (lane >= off) x += y; }
    if (lane == 63) wsum[wv] = x;
    __syncthreads();
    if (wv == 0) {
      int t = (lane < 16) ? wsum[lane] : 0;
#pragma unroll
      for (int off = 1; off < 16; off <<= 1) { int y = __shfl_up(t, off); if (lane >= off) t += y; }
      if (lane < 16) wsum[lane] = t;
    }
    __syncthreads();
    int offs = wv ? wsum[wv - 1] : 0;
    int tot = wsum[15];
    if (idx < n) indptr[idx] = run + offs + x - v;
    run += tot;
    __syncthreads();
  }
  if (tid == 0) indptr[n] = run;
}

__global__ void fill_kernel(const int* __restrict__ src, const int* __restrict__ dst,
                            const int* __restrict__ indptr, int* __restrict__ fillc,
                            int* __restrict__ srcl, int E, int EP)
{
  int e = blockIdx.x * blockDim.x + threadIdx.x;
  if (e >= EP) return;
  int d, s;
  if (e < E) { d = dst[e]; s = src[e]; } else { d = e - E; s = e - E; }
  int pos = atomicAdd(&fillc[d], 1);
  srcl[indptr[d] + pos] = s;
}

// ============ GAT: per-node attention logits (bf16 xh) ============
__global__ void gat_att_kernel(const unsigned short* __restrict__ xhb,
                               const float* __restrict__ attS, const float* __restrict__ attD,
                               float* __restrict__ aS, float* __restrict__ aD, int n)
{
  int idx = blockIdx.x * blockDim.x + threadIdx.x;
  if (idx >= n * 4) return;
  int nn = idx >> 2, hd = idx & 3;
  const uint4* xr = (const uint4*)(xhb + (size_t)nn * 128 + hd * 32);
  const float* as_ = attS + hd * 32;
  const float* ad_ = attD + hd * 32;
  float s = 0.f, d = 0.f;
#pragma unroll
  for (int w = 0; w < 4; ++w) {
    uint4 v = xr[w];
    unsigned int u[4] = {v.x, v.y, v.z, v.w};
#pragma unroll
    for (int c = 0; c < 4; ++c) {
      float lo = b2f((unsigned short)(u[c] & 0xffff));
      float hi = b2f((unsigned short)(u[c] >> 16));
      int o = w * 8 + c * 2;
      s = fmaf(lo, as_[o], s);     d = fmaf(lo, ad_[o], d);
      s = fmaf(hi, as_[o + 1], s); d = fmaf(hi, ad_[o + 1], d);
    }
  }
  aS[idx] = s; aD[idx] = d;
}

// ============ GAT: fused softmax + weighted gather (wave per dst) ============
// Pass A (lane-parallel): per-head max. Pass B (wave-serial over edges):
// one exp per lane (own head), accumulate sum + unnormalized gather; scale at end.
__global__ __launch_bounds__(256)
void gat_fused_kernel(const unsigned short* __restrict__ xhb,
                      const float* __restrict__ aS, const float* __restrict__ aD,
                      const int* __restrict__ indptr, const int* __restrict__ srcl,
                      const float* __restrict__ bgat, unsigned short* __restrict__ outb,
                      int ldo, int n)
{
  int wid = (int)((blockIdx.x * (size_t)blockDim.x + threadIdx.x) >> 6);
  int lane = threadIdx.x & 63;
  if (wid >= n) return;
  int eb = indptr[wid], ee = indptr[wid + 1];
  float4 ad = ld4(aD + wid * 4);
  // pass A: per-head max (lane-parallel)
  float m0 = -3e38f, m1 = -3e38f, m2 = -3e38f, m3 = -3e38f;
  for (int i = eb + lane; i < ee; i += 64) {
    int s = srcl[i];
    float4 as = ld4(aS + s * 4);
    float e0 = as.x + ad.x; e0 = e0 > 0.f ? e0 : 0.2f * e0; m0 = fmaxf(m0, e0);
    float e1 = as.y + ad.y; e1 = e1 > 0.f ? e1 : 0.2f * e1; m1 = fmaxf(m1, e1);
    float e2 = as.z + ad.z; e2 = e2 > 0.f ? e2 : 0.2f * e2; m2 = fmaxf(m2, e2);
    float e3 = as.w + ad.w; e3 = e3 > 0.f ? e3 : 0.2f * e3; m3 = fmaxf(m3, e3);
  }
#pragma unroll
  for (int off = 32; off; off >>= 1) {
    m0 = fmaxf(m0, __shfl_xor(m0, off)); m1 = fmaxf(m1, __shfl_xor(m1, off));
    m2 = fmaxf(m2, __shfl_xor(m2, off)); m3 = fmaxf(m3, __shfl_xor(m3, off));
  }
  int hsel = lane >> 4;
  float mh  = (hsel == 0) ? m0 : (hsel == 1) ? m1 : (hsel == 2) ? m2 : m3;
  float adh = (hsel == 0) ? ad.x : (hsel == 1) ? ad.y : (hsel == 2) ? ad.z : ad.w;
  // pass B: serial over edges; p computed once per lane (own head)
  float sum = 0.f, acc0 = 0.f, acc1 = 0.f;
  for (int i = eb; i < ee; ++i) {
    int s = srcl[i];
    float e = aS[s * 4 + hsel] + adh;
    e = e > 0.f ? e : 0.2f * e;
    float p = __expf(e - mh);
    sum += p;
    unsigned int px = *(const unsigned int*)(xhb + (size_t)s * 128 + lane * 2);
    acc0 = fmaf(p, b2f((unsigned short)(px & 0xffff)), acc0);
    acc1 = fmaf(p, b2f((unsigned short)(px >> 16)), acc1);
  }
  float dv = 1.f / (sum + 1e-16f);
  float ox = acc0 * dv + bgat[lane * 2];
  float oy = acc1 * dv + bgat[lane * 2 + 1];
  unsigned int pk = (unsigned int)f2b(ox) | ((unsigned int)f2b(oy) << 16);
  *reinterpret_cast<unsigned int*>(outb + (size_t)wid * ldo + lane * 2) = pk;
}

// ============ impact head layer 2 + |.| mean ============
__global__ __launch_bounds__(256)
void impact_out_kernel(const float* __restrict__ hid, const float* __restrict__ W2,
                       const float* __restrict__ b2, float* __restrict__ outp,
                       float* __restrict__ total, float wk, int n)
{
  __shared__ float red[256];
  int idx = blockIdx.x * 256 + threadIdx.x;
  float part = 0.f;
  if (idx < n) {
    const float* h = hid + (size_t)idx * 64;
    float o0 = b2[0], o1 = b2[1], o2 = b2[2];
#pragma unroll 8
    for (int k = 0; k < 64; ++k) {
      float v = h[k];
      o0 = fmaf(v, W2[k * 3 + 0], o0);
      o1 = fmaf(v, W2[k * 3 + 1], o1);
      o2 = fmaf(v, W2[k * 3 + 2], o2);
    }
    outp[(size_t)idx * 3 + 0] = o0;
    outp[(size_t)idx * 3 + 1] = o1;
    outp[(size_t)idx * 3 + 2] = o2;
    part = fabsf(o0) + fabsf(o1) + fabsf(o2);
  }
  red[threadIdx.x] = part;
  __syncthreads();
  for (int s = 128; s; s >>= 1) {
    if (threadIdx.x < s) red[threadIdx.x] += red[threadIdx.x + s];
    __syncthreads();
  }
  if (threadIdx.x == 0) atomicAdd(total, red[0] * wk);
}

// ============ host ============
extern "C" void kernel_launch(void* const* d_in, const int* in_sizes, int n_in,
                              void* d_out, int out_size, void* d_ws, size_t ws_size,
                              hipStream_t stream)
{
  const float* x     = (const float*)d_in[0];
  const int*   ei    = (const int*)  d_in[1];
  const float* mask  = (const float*)d_in[2];
  const float* itype = (const float*)d_in[3];
  const float* Wenc  = (const float*)d_in[4];
  const float* benc  = (const float*)d_in[5];
  const float* Wgat  = (const float*)d_in[6];
  const float* attS  = (const float*)d_in[7];
  const float* attD  = (const float*)d_in[8];
  const float* bgat  = (const float*)d_in[9];
  const float* W1    = (const float*)d_in[10];
  const float* b1    = (const float*)d_in[11];
  const float* W2    = (const float*)d_in[12];
  const float* b2    = (const float*)d_in[13];
  const float* Wih0  = (const float*)d_in[14];
  const float* Whh0  = (const float*)d_in[15];
  const float* bih0  = (const float*)d_in[16];
  const float* bhh0  = (const float*)d_in[17];
  const float* Wih1  = (const float*)d_in[18];
  const float* Whh1  = (const float*)d_in[19];
  const float* bih1  = (const float*)d_in[20];
  const float* bhh1  = (const float*)d_in[21];

  const int N  = in_sizes[0] / 128;
  const int E  = in_sizes[1] / 2;
  const int EP = E + N;

  float* out      = (float*)d_out;
  float* impacts  = out;
  float* temporal = out + (size_t)3 * N * 3;     // [N][3][128], ld 384
  float* hlast    = temporal + (size_t)N * 384;  // [N][128]
  float* total    = hlast + (size_t)N * 128;

  // ---- workspace layout ----
  float* ws = (float*)d_ws;
  float* c0 = ws;                                 // N*128 f (encoder scratch, then aS/aD)
  float* c1 = c0 + (size_t)N * 128;               // N*128 f (impact hidden)
  unsigned short* tempb = (unsigned short*)(c1 + (size_t)N * 128);  // [N][3][128] bf16
  unsigned short* hb0   = tempb + (size_t)N * 384;                  // N*128 bf16 (enc out)
  unsigned short* xhb   = hb0 + (size_t)N * 128;                    // N*128 bf16 (xh)
  int* indptr = (int*)(xhb + (size_t)N * 128);    // N+1
  int* fillc  = indptr + (N + 1);                 // N
  int* srcl   = fillc + N;                        // EP
  size_t ip = (size_t)((srcl + EP) - (int*)ws);
  ip = (ip + 7) & ~(size_t)7;
  unsigned short* frags = (unsigned short*)((int*)ws + ip);
  unsigned short* WencF = frags;                  // 16384
  unsigned short* WgatF = WencF + 16384;          // 3*16384
  unsigned short* W1F   = WgatF + 3 * 16384;      // 3*8192
  unsigned short* L0F   = W1F + 3 * 8192;         // 131072
  unsigned short* L1F   = L0F + 131072;           // 131072

  float* regA = c1;
  float* aS   = c0;
  float* aD   = c0 + (size_t)N * 4;

  size_t need = ((size_t)N * 128 * 2) * 4 + (size_t)N * 384 * 2 + (size_t)N * 128 * 2 * 2
              + ((size_t)2 * N + 1 + EP + 8) * 4 + (size_t)(16384 * 4 + 8192 * 3 + 131072 * 2) * 2 + 64;
  if (ws_size < need) return;

  const int* esrc = ei;
  const int* edst = ei + E;
  const int rowTiles = (N + 63) / 64;

  // ---- build weight fragments ----
  build_frag_kmajor<<<64, 256, 0, stream>>>(Wenc, 128, WencF, 4, 8);
  for (int k = 0; k < 3; ++k) {
    build_frag_kmajor<<<64, 256, 0, stream>>>(Wgat + (size_t)k * 16384, 128, WgatF + (size_t)k * 16384, 4, 8);
    build_frag_kmajor<<<32, 256, 0, stream>>>(W1 + (size_t)k * 8192, 64, W1F + (size_t)k * 8192, 4, 4);
  }
  build_frag_lstm3<<<512, 256, 0, stream>>>(Wih0, Whh0, L0F);
  build_frag_lstm3<<<512, 256, 0, stream>>>(Wih1, Whh1, L1F);

  // ---- CSR by destination (self-loops appended) ----
  hipMemsetAsync(fillc, 0, (size_t)N * sizeof(int), stream);
  count_kernel<<<(EP + 255) / 256, 256, 0, stream>>>(edst, fillc, E, EP);
  scan_kernel<<<1, 1024, 0, stream>>>(fillc, indptr, N);
  hipMemsetAsync(fillc, 0, (size_t)N * sizeof(int), stream);
  fill_kernel<<<(EP + 255) / 256, 256, 0, stream>>>(esrc, edst, indptr, fillc, srcl, E, EP);

  // ---- encoder ----
  gemm_mfma<8, 4, 0, 0, 0><<<dim3(rowTiles, 1), 256, 0, stream>>>(
      x, 128, WencF, 8, c0, nullptr, 128, nullptr, N);
  encoder_finish_kernel<<<(N * 128 + 255) / 256, 256, 0, stream>>>(c0, itype, mask, Wenc, benc, hb0, N);

  hipMemsetAsync(total, 0, sizeof(float), stream);

  const int waveGrid = (N * 64 + 255) / 256;

  // ---- 3 GAT hops + impact heads ----
  for (int k = 0; k < 3; ++k) {
    const unsigned short* hinb = (k == 0) ? hb0 : (tempb + (size_t)(k - 1) * 128);
    int ldin = (k == 0) ? 128 : 384;
    gemm_mfma<8, 4, 1, 0, 1><<<dim3(rowTiles, 1), 256, 0, stream>>>(
        hinb, ldin, WgatF + (size_t)k * 16384, 8, nullptr, xhb, 128, nullptr, N);
    gat_att_kernel<<<(N * 4 + 255) / 256, 256, 0, stream>>>(xhb, attS + k * 128, attD + k * 128, aS, aD, N);
    gat_fused_kernel<<<waveGrid, 256, 0, stream>>>(xhb, aS, aD, indptr, srcl, bgat + k * 128,
                                                   tempb + (size_t)k * 128, 384, N);
    gemm_mfma<4, 4, 0, 1, 1><<<dim3(rowTiles, 1), 256, 0, stream>>>(
        tempb + (size_t)k * 128, 384, W1F + (size_t)k * 8192, 4,
        regA, nullptr, 64, b1 + k * 64, N);
    float wk = ((k == 0) ? 1.f : (k == 1) ? 0.5f : 0.25f) / (3.0f * (float)N);
    impact_out_kernel<<<(N + 255) / 256, 256, 0, stream>>>(regA, W2 + k * 192, b2 + k * 3,
                                                           impacts + (size_t)k * N * 3, total, wk, N);
  }

  // ---- fully fused LSTM (r5 structure + coalesced epilogue) ----
  lstm_fused<<<rowTiles, 512, 0, stream>>>(tempb, L0F, L1F, bih0, bhh0, bih1, bhh1,
                                           temporal, hlast, N);
}

// Round 13
// 1717.011 us; speedup vs baseline: 1.9322x; 1.1504x over previous
//
#include <hip/hip_runtime.h>

typedef __attribute__((ext_vector_type(8))) short short8;
typedef __attribute__((ext_vector_type(4))) float f32x4;

__device__ __forceinline__ float4 ld4(const float* p){ return *reinterpret_cast<const float4*>(p); }
__device__ __forceinline__ void st4(float* p, const float4& v){ *reinterpret_cast<float4*>(p) = v; }

__device__ __forceinline__ unsigned short f2b(float x){
  unsigned int u = __float_as_uint(x);
  unsigned int r = (u + 0x7fffu + ((u >> 16) & 1u)) >> 16;
  return (unsigned short)r;
}
__device__ __forceinline__ float b2f(unsigned short b){
  return __uint_as_float(((unsigned int)b) << 16);
}

__device__ __forceinline__ float fsigmoid(float x){ return 1.f / (1.f + __expf(-x)); }
__device__ __forceinline__ float ftanh(float x){ return 1.f - 2.f / (1.f + __expf(2.f * x)); }

__device__ __forceinline__ short8 cvt_frag(float4 f0, float4 f1){
  short8 a;
  a[0]=(short)f2b(f0.x); a[1]=(short)f2b(f0.y); a[2]=(short)f2b(f0.z); a[3]=(short)f2b(f0.w);
  a[4]=(short)f2b(f1.x); a[5]=(short)f2b(f1.y); a[6]=(short)f2b(f1.z); a[7]=(short)f2b(f1.w);
  return a;
}

// ============ weight fragmentization ============
__global__ void build_frag_kmajor(const float* __restrict__ B, int ldb,
                                  unsigned short* __restrict__ BF, int KB, int CTG)
{
  int idx = blockIdx.x * 256 + threadIdx.x;
  int total = KB * CTG * 512;
  if (idx >= total) return;
  int j = idx & 7, lane = (idx >> 3) & 63, rest = idx >> 9;
  int ctg = rest % CTG, kb = rest / CTG;
  int k = kb * 32 + ((lane >> 4) << 3) + j;
  int col = ctg * 16 + (lane & 15);
  BF[idx] = f2b(B[(size_t)k * ldb + col]);
}

// LSTM wave-slice layout (8 waves x 16 j-cols each), round-5 layout
__global__ void build_frag_lstm3(const float* __restrict__ Wih, const float* __restrict__ Whh,
                                 unsigned short* __restrict__ BF)
{
  int idx = blockIdx.x * 256 + threadIdx.x;
  if (idx >= 131072) return;
  int j = idx & 7, lane = (idx >> 3) & 63;
  int g = (idx >> 9) & 3, kb = (idx >> 11) & 7, w = idx >> 14;
  int col = g * 128 + w * 16 + (lane & 15);
  int k = kb * 32 + ((lane >> 4) << 3) + j;
  float v = (k < 128) ? Wih[(size_t)col * 128 + k] : Whh[(size_t)col * 128 + (k - 128)];
  BF[idx] = f2b(v);
}

// ============ generic MFMA GEMM ============
template<int CT, int KB, int OUTBF, int RELU, int ABF16>
__global__ __launch_bounds__(256)
void gemm_mfma(const void* __restrict__ Av, int lda,
               const unsigned short* __restrict__ BF, int ctgTot,
               float* __restrict__ Cf, unsigned short* __restrict__ Cb, int ldc,
               const float* __restrict__ bias, int nrows)
{
  const int tid = threadIdx.x, lane = tid & 63, wid = tid >> 6;
  const int row0 = blockIdx.x * 64 + wid * 16;
  const int cg = blockIdx.y * CT;
  const int r = row0 + (lane & 15);
  const bool rok = r < nrows;
  const int koff = (lane >> 4) << 3;

  f32x4 acc[CT];
#pragma unroll
  for (int ct = 0; ct < CT; ++ct) {
    float b = bias ? bias[(cg + ct) * 16 + (lane & 15)] : 0.f;
    acc[ct] = (f32x4){b, b, b, b};
  }

#pragma unroll
  for (int kb = 0; kb < KB; ++kb) {
    short8 a = {};
    if (rok) {
      if (ABF16) {
        a = *(const short8*)((const unsigned short*)Av + (size_t)r * lda + kb * 32 + koff);
      } else {
        const float* p = (const float*)Av + (size_t)r * lda + kb * 32 + koff;
        a = cvt_frag(ld4(p), ld4(p + 4));
      }
    }
#pragma unroll
    for (int ct = 0; ct < CT; ++ct) {
      const short8 b = *(const short8*)(BF + ((size_t)(kb * ctgTot + cg + ct) * 64 + lane) * 8);
      acc[ct] = __builtin_amdgcn_mfma_f32_16x16x32_bf16(a, b, acc[ct], 0, 0, 0);
    }
  }

  const int orow = row0 + ((lane >> 4) << 2);
#pragma unroll
  for (int ct = 0; ct < CT; ++ct) {
    int col = (cg + ct) * 16 + (lane & 15);
#pragma unroll
    for (int rg = 0; rg < 4; ++rg) {
      int rr = orow + rg;
      if (rr >= nrows) continue;
      float v = acc[ct][rg];
      if (RELU) v = fmaxf(v, 0.f);
      if (OUTBF) Cb[(size_t)rr * ldc + col] = f2b(v);
      else       Cf[(size_t)rr * ldc + col] = v;
    }
  }
}

// ============ fully fused 2-layer x T=3 LSTM (r12: r5 structure + coalesced epilogue) ============
__global__ __launch_bounds__(512, 2)
void lstm_fused(const unsigned short* __restrict__ tempb,
                const unsigned short* __restrict__ L0F, const unsigned short* __restrict__ L1F,
                const float* __restrict__ bih0, const float* __restrict__ bhh0,
                const float* __restrict__ bih1, const float* __restrict__ bhh1,
                float* __restrict__ temporal, float* __restrict__ hlast, int nrows)
{
  __shared__ unsigned short h0b[8192];
  __shared__ unsigned short h1b[8192];
  __shared__ float h1f[64 * 132];
  const int tid = threadIdx.x, lane = tid & 63, w = tid >> 6;
  const int row0 = blockIdx.x * 64;
  const int rbase = lane & 15;
  const int koff = (lane >> 4) << 3;
  const int c15 = lane & 15;
  const int jw = w * 16;

  float bs0[4], bs1[4];
#pragma unroll
  for (int g = 0; g < 4; ++g) {
    int col = g * 128 + jw + c15;
    bs0[g] = bih0[col] + bhh0[col];
    bs1[g] = bih1[col] + bhh1[col];
  }

  f32x4 c0[4], c1[4];
#pragma unroll
  for (int i = 0; i < 4; ++i) { c0[i] = (f32x4){0,0,0,0}; c1[i] = (f32x4){0,0,0,0}; }

  const unsigned short* BF0 = L0F + (size_t)w * 16384;
  const unsigned short* BF1 = L1F + (size_t)w * 16384;

  f32x4 acc[4][4];

  for (int t = 0; t < 3; ++t) {
    // ---------- layer 0 ----------
#pragma unroll
    for (int rf = 0; rf < 4; ++rf)
#pragma unroll
      for (int g = 0; g < 4; ++g) acc[rf][g] = (f32x4){bs0[g], bs0[g], bs0[g], bs0[g]};

#pragma unroll
    for (int kb = 0; kb < 4; ++kb) {
      short8 a[4];
#pragma unroll
      for (int rf = 0; rf < 4; ++rf) {
        int r = row0 + rf * 16 + rbase;
        a[rf] = (r < nrows) ? *(const short8*)(tempb + (size_t)r * 384 + t * 128 + kb * 32 + koff)
                            : (short8){0,0,0,0,0,0,0,0};
      }
#pragma unroll
      for (int g = 0; g < 4; ++g) {
        const short8 b = *(const short8*)(BF0 + (((size_t)kb * 4 + g) * 64 + lane) * 8);
#pragma unroll
        for (int rf = 0; rf < 4; ++rf)
          acc[rf][g] = __builtin_amdgcn_mfma_f32_16x16x32_bf16(a[rf], b, acc[rf][g], 0, 0, 0);
      }
    }
    if (t > 0) {
#pragma unroll
      for (int kb = 4; kb < 8; ++kb) {
        short8 a[4];
#pragma unroll
        for (int rf = 0; rf < 4; ++rf) {
          int rl = rf * 16 + rbase;
          int kk = (kb - 4) * 32 + koff;
          a[rf] = *(const short8*)(h0b + rl * 128 + (kk ^ ((rl & 7) << 3)));
        }
#pragma unroll
        for (int g = 0; g < 4; ++g) {
          const short8 b = *(const short8*)(BF0 + (((size_t)kb * 4 + g) * 64 + lane) * 8);
#pragma unroll
          for (int rf = 0; rf < 4; ++rf)
            acc[rf][g] = __builtin_amdgcn_mfma_f32_16x16x32_bf16(a[rf], b, acc[rf][g], 0, 0, 0);
        }
      }
    }

    __syncthreads();  // A

#pragma unroll
    for (int rf = 0; rf < 4; ++rf) {
      int j = jw + c15;
#pragma unroll
      for (int rg = 0; rg < 4; ++rg) {
        float si = fsigmoid(acc[rf][0][rg]);
        float sf = fsigmoid(acc[rf][1][rg]);
        float gg = ftanh(acc[rf][2][rg]);
        float so = fsigmoid(acc[rf][3][rg]);
        float c = sf * c0[rf][rg] + si * gg;
        c0[rf][rg] = c;
        float hh = so * ftanh(c);
        int rl = rf * 16 + ((lane >> 4) << 2) + rg;
        h0b[rl * 128 + (j ^ ((rl & 7) << 3))] = f2b(hh);
      }
    }

    __syncthreads();  // B

    // ---------- layer 1 ----------
#pragma unroll
    for (int rf = 0; rf < 4; ++rf)
#pragma unroll
      for (int g = 0; g < 4; ++g) acc[rf][g] = (f32x4){bs1[g], bs1[g], bs1[g], bs1[g]};

#pragma unroll
    for (int kb = 0; kb < 4; ++kb) {
      short8 a[4];
#pragma unroll
      for (int rf = 0; rf < 4; ++rf) {
        int rl = rf * 16 + rbase;
        int kk = kb * 32 + koff;
        a[rf] = *(const short8*)(h0b + rl * 128 + (kk ^ ((rl & 7) << 3)));
      }
#pragma unroll
      for (int g = 0; g < 4; ++g) {
        const short8 b = *(const short8*)(BF1 + (((size_t)kb * 4 + g) * 64 + lane) * 8);
#pragma unroll
        for (int rf = 0; rf < 4; ++rf)
          acc[rf][g] = __builtin_amdgcn_mfma_f32_16x16x32_bf16(a[rf], b, acc[rf][g], 0, 0, 0);
      }
    }
    if (t > 0) {
#pragma unroll
      for (int kb = 4; kb < 8; ++kb) {
        short8 a[4];
#pragma unroll
        for (int rf = 0; rf < 4; ++rf) {
          int rl = rf * 16 + rbase;
          int kk = (kb - 4) * 32 + koff;
          a[rf] = *(const short8*)(h1b + rl * 128 + (kk ^ ((rl & 7) << 3)));
        }
#pragma unroll
        for (int g = 0; g < 4; ++g) {
          const short8 b = *(const short8*)(BF1 + (((size_t)kb * 4 + g) * 64 + lane) * 8);
#pragma unroll
          for (int rf = 0; rf < 4; ++rf)
            acc[rf][g] = __builtin_amdgcn_mfma_f32_16x16x32_bf16(a[rf], b, acc[rf][g], 0, 0, 0);
        }
      }
    }

    __syncthreads();  // C

#pragma unroll
    for (int rf = 0; rf < 4; ++rf) {
      int j = jw + c15;
#pragma unroll
      for (int rg = 0; rg < 4; ++rg) {
        float si = fsigmoid(acc[rf][0][rg]);
        float sf = fsigmoid(acc[rf][1][rg]);
        float gg = ftanh(acc[rf][2][rg]);
        float so = fsigmoid(acc[rf][3][rg]);
        float c = sf * c1[rf][rg] + si * gg;
        c1[rf][rg] = c;
        float hh = so * ftanh(c);
        int rl = rf * 16 + ((lane >> 4) << 2) + rg;
        h1b[rl * 128 + (j ^ ((rl & 7) << 3))] = f2b(hh);
        h1f[rl * 132 + j] = hh;
      }
    }

    __syncthreads();  // D

#pragma unroll
    for (int k = 0; k < 4; ++k) {
      int idx = tid + k * 512;
      int row = idx >> 5;
      int c4 = (idx & 31) << 2;
      int r = row0 + row;
      if (r < nrows) {
        float4 v = ld4(&h1f[row * 132 + c4]);
        st4(&temporal[(size_t)r * 384 + t * 128 + c4], v);
        if (t == 2) st4(&hlast[(size_t)r * 128 + c4], v);
      }
    }
  }
}

// ============ encoder tail ============
__global__ void encoder_finish_kernel(const float* __restrict__ pre, const float* __restrict__ itype,
                                      const float* __restrict__ mask, const float* __restrict__ Wenc,
                                      const float* __restrict__ benc, unsigned short* __restrict__ hb, int n)
{
  int idx = blockIdx.x * blockDim.x + threadIdx.x;
  if (idx >= n * 128) return;
  int nn = idx >> 7, j = idx & 127;
  float v = pre[idx]
          + itype[nn * 3 + 0] * Wenc[128 * 128 + j]
          + itype[nn * 3 + 1] * Wenc[129 * 128 + j]
          + itype[nn * 3 + 2] * Wenc[130 * 128 + j]
          + benc[j];
  hb[idx] = f2b(fmaxf(v, 0.f) * mask[nn]);
}

// ============ CSR build ============
__global__ void count_kernel(const int* __restrict__ dst, int* __restrict__ cnt, int E, int EP)
{
  int e = blockIdx.x * blockDim.x + threadIdx.x;
  if (e >= EP) return;
  int d = (e < E) ? dst[e] : (e - E);
  atomicAdd(&cnt[d], 1);
}

// two-level scan: S1 per-1024-block exclusive scan + block totals
__global__ __launch_bounds__(1024)
void scan1_kernel(const int* __restrict__ cnt, int* __restrict__ indptr,
                  int* __restrict__ bsum, int n)
{
  __shared__ int wsum[16];
  int tid = threadIdx.x;
  int lane = tid & 63, wv = tid >> 6;
  int idx = blockIdx.x * 1024 + tid;
  int v = (idx < n) ? cnt[idx] : 0;
  int x = v;
#pragma unroll
  for (int off = 1; off < 64; off <<= 1) { int y = __shfl_up(x, off); if (lane >= off) x += y; }
  if (lane == 63) wsum[wv] = x;
  __syncthreads();
  if (wv == 0) {
    int t = (lane < 16) ? wsum[lane] : 0;
#pragma unroll
    for (int off = 1; off < 16; off <<= 1) { int y = __shfl_up(t, off); if (lane >= off) t += y; }
    if (lane < 16) wsum[lane] = t;
  }
  __syncthreads();
  int offs = wv ? wsum[wv - 1] : 0;
  if (idx < n) indptr[idx] = offs + x - v;
  if (tid == 0) bsum[blockIdx.x] = wsum[15];
}

// S2: serial scan of block sums (nb ~ 98), writes total to indptr[n]
__global__ void scan2_kernel(int* __restrict__ bsum, int* __restrict__ indptr, int nb, int n)
{
  if (threadIdx.x == 0 && blockIdx.x == 0) {
    int run = 0;
    for (int i = 0; i < nb; ++i) { int t = bsum[i]; bsum[i] = run; run += t; }
    indptr[n] = run;
  }
}

// S3: add block prefix
__global__ __launch_bounds__(1024)
void scan3_kernel(int* __restrict__ indptr, const int* __restrict__ bsum, int n)
{
  int idx = blockIdx.x * 1024 + threadIdx.x;
  if (idx < n) indptr[idx] += bsum[blockIdx.x];
}

__global__ void fill_kernel(const int* __restrict__ src, const int* __restrict__ dst,
                            const int* __restrict__ indptr, int* __restrict__ fillc,
                            int* __restrict__ srcl, int E, int EP)
{
  int e = blockIdx.x * blockDim.x + threadIdx.x;
  if (e >= EP) return;
  int d, s;
  if (e < E) { d = dst[e]; s = src[e]; } else { d = e - E; s = e - E; }
  int pos = atomicAdd(&fillc[d], 1);
  srcl[indptr[d] + pos] = s;
}

// ============ GAT: per-node attention logits (bf16 xh) ============
__global__ void gat_att_kernel(const unsigned short* __restrict__ xhb,
                               const float* __restrict__ attS, const float* __restrict__ attD,
                               float* __restrict__ aS, float* __restrict__ aD, int n)
{
  int idx = blockIdx.x * blockDim.x + threadIdx.x;
  if (idx >= n * 4) return;
  int nn = idx >> 2, hd = idx & 3;
  const uint4* xr = (const uint4*)(xhb + (size_t)nn * 128 + hd * 32);
  const float* as_ = attS + hd * 32;
  const float* ad_ = attD + hd * 32;
  float s = 0.f, d = 0.f;
#pragma unroll
  for (int w = 0; w < 4; ++w) {
    uint4 v = xr[w];
    unsigned int u[4] = {v.x, v.y, v.z, v.w};
#pragma unroll
    for (int c = 0; c < 4; ++c) {
      float lo = b2f((unsigned short)(u[c] & 0xffff));
      float hi = b2f((unsigned short)(u[c] >> 16));
      int o = w * 8 + c * 2;
      s = fmaf(lo, as_[o], s);     d = fmaf(lo, ad_[o], d);
      s = fmaf(hi, as_[o + 1], s); d = fmaf(hi, ad_[o + 1], d);
    }
  }
  aS[idx] = s; aD[idx] = d;
}

// ============ GAT: fused softmax + weighted gather (wave per dst), x2 unrolled ============
__global__ __launch_bounds__(256)
void gat_fused_kernel(const unsigned short* __restrict__ xhb,
                      const float* __restrict__ aS, const float* __restrict__ aD,
                      const int* __restrict__ indptr, const int* __restrict__ srcl,
                      const float* __restrict__ bgat, unsigned short* __restrict__ outb,
                      int ldo, int n)
{
  int wid = (int)((blockIdx.x * (size_t)blockDim.x + threadIdx.x) >> 6);
  int lane = threadIdx.x & 63;
  if (wid >= n) return;
  int eb = indptr[wid], ee = indptr[wid + 1];
  float4 ad = ld4(aD + wid * 4);
  float m0 = -3e38f, m1 = -3e38f, m2 = -3e38f, m3 = -3e38f;
  for (int i = eb + lane; i < ee; i += 64) {
    int s = srcl[i];
    float4 as = ld4(aS + s * 4);
    float e0 = as.x + ad.x; e0 = e0 > 0.f ? e0 : 0.2f * e0; m0 = fmaxf(m0, e0);
    float e1 = as.y + ad.y; e1 = e1 > 0.f ? e1 : 0.2f * e1; m1 = fmaxf(m1, e1);
    float e2 = as.z + ad.z; e2 = e2 > 0.f ? e2 : 0.2f * e2; m2 = fmaxf(m2, e2);
    float e3 = as.w + ad.w; e3 = e3 > 0.f ? e3 : 0.2f * e3; m3 = fmaxf(m3, e3);
  }
#pragma unroll
  for (int off = 32; off; off >>= 1) {
    m0 = fmaxf(m0, __shfl_xor(m0, off)); m1 = fmaxf(m1, __shfl_xor(m1, off));
    m2 = fmaxf(m2, __shfl_xor(m2, off)); m3 = fmaxf(m3, __shfl_xor(m3, off));
  }
  int hsel = lane >> 4;
  float mh  = (hsel == 0) ? m0 : (hsel == 1) ? m1 : (hsel == 2) ? m2 : m3;
  float adh = (hsel == 0) ? ad.x : (hsel == 1) ? ad.y : (hsel == 2) ? ad.z : ad.w;
  float sum = 0.f, acc0 = 0.f, acc1 = 0.f;
  int i = eb;
  for (; i + 1 < ee; i += 2) {
    int s0 = srcl[i], s1 = srcl[i + 1];
    float e0 = aS[s0 * 4 + hsel] + adh; e0 = e0 > 0.f ? e0 : 0.2f * e0;
    float e1 = aS[s1 * 4 + hsel] + adh; e1 = e1 > 0.f ? e1 : 0.2f * e1;
    unsigned int px0 = *(const unsigned int*)(xhb + (size_t)s0 * 128 + lane * 2);
    unsigned int px1 = *(const unsigned int*)(xhb + (size_t)s1 * 128 + lane * 2);
    float p0 = __expf(e0 - mh);
    float p1 = __expf(e1 - mh);
    sum += p0 + p1;
    acc0 = fmaf(p0, b2f((unsigned short)(px0 & 0xffff)), acc0);
    acc1 = fmaf(p0, b2f((unsigned short)(px0 >> 16)), acc1);
    acc0 = fmaf(p1, b2f((unsigned short)(px1 & 0xffff)), acc0);
    acc1 = fmaf(p1, b2f((unsigned short)(px1 >> 16)), acc1);
  }
  if (i < ee) {
    int s = srcl[i];
    float e = aS[s * 4 + hsel] + adh; e = e > 0.f ? e : 0.2f * e;
    float p = __expf(e - mh);
    sum += p;
    unsigned int px = *(const unsigned int*)(xhb + (size_t)s * 128 + lane * 2);
    acc0 = fmaf(p, b2f((unsigned short)(px & 0xffff)), acc0);
    acc1 = fmaf(p, b2f((unsigned short)(px >> 16)), acc1);
  }
  float dv = 1.f / (sum + 1e-16f);
  float ox = acc0 * dv + bgat[lane * 2];
  float oy = acc1 * dv + bgat[lane * 2 + 1];
  unsigned int pk = (unsigned int)f2b(ox) | ((unsigned int)f2b(oy) << 16);
  *reinterpret_cast<unsigned int*>(outb + (size_t)wid * ldo + lane * 2) = pk;
}

// ============ impact head layer 2 + |.| mean ============
__global__ __launch_bounds__(256)
void impact_out_kernel(const float* __restrict__ hid, const float* __restrict__ W2,
                       const float* __restrict__ b2, float* __restrict__ outp,
                       float* __restrict__ total, float wk, int n)
{
  __shared__ float red[256];
  int idx = blockIdx.x * 256 + threadIdx.x;
  float part = 0.f;
  if (idx < n) {
    const float* h = hid + (size_t)idx * 64;
    float o0 = b2[0], o1 = b2[1], o2 = b2[2];
#pragma unroll 8
    for (int k = 0; k < 64; ++k) {
      float v = h[k];
      o0 = fmaf(v, W2[k * 3 + 0], o0);
      o1 = fmaf(v, W2[k * 3 + 1], o1);
      o2 = fmaf(v, W2[k * 3 + 2], o2);
    }
    outp[(size_t)idx * 3 + 0] = o0;
    outp[(size_t)idx * 3 + 1] = o1;
    outp[(size_t)idx * 3 + 2] = o2;
    part = fabsf(o0) + fabsf(o1) + fabsf(o2);
  }
  red[threadIdx.x] = part;
  __syncthreads();
  for (int s = 128; s; s >>= 1) {
    if (threadIdx.x < s) red[threadIdx.x] += red[threadIdx.x + s];
    __syncthreads();
  }
  if (threadIdx.x == 0) atomicAdd(total, red[0] * wk);
}

// ============ host ============
extern "C" void kernel_launch(void* const* d_in, const int* in_sizes, int n_in,
                              void* d_out, int out_size, void* d_ws, size_t ws_size,
                              hipStream_t stream)
{
  const float* x     = (const float*)d_in[0];
  const int*   ei    = (const int*)  d_in[1];
  const float* mask  = (const float*)d_in[2];
  const float* itype = (const float*)d_in[3];
  const float* Wenc  = (const float*)d_in[4];
  const float* benc  = (const float*)d_in[5];
  const float* Wgat  = (const float*)d_in[6];
  const float* attS  = (const float*)d_in[7];
  const float* attD  = (const float*)d_in[8];
  const float* bgat  = (const float*)d_in[9];
  const float* W1    = (const float*)d_in[10];
  const float* b1    = (const float*)d_in[11];
  const float* W2    = (const float*)d_in[12];
  const float* b2    = (const float*)d_in[13];
  const float* Wih0  = (const float*)d_in[14];
  const float* Whh0  = (const float*)d_in[15];
  const float* bih0  = (const float*)d_in[16];
  const float* bhh0  = (const float*)d_in[17];
  const float* Wih1  = (const float*)d_in[18];
  const float* Whh1  = (const float*)d_in[19];
  const float* bih1  = (const float*)d_in[20];
  const float* bhh1  = (const float*)d_in[21];

  const int N  = in_sizes[0] / 128;
  const int E  = in_sizes[1] / 2;
  const int EP = E + N;

  float* out      = (float*)d_out;
  float* impacts  = out;
  float* temporal = out + (size_t)3 * N * 3;     // [N][3][128], ld 384
  float* hlast    = temporal + (size_t)N * 384;  // [N][128]
  float* total    = hlast + (size_t)N * 128;

  // ---- workspace layout ----
  float* ws = (float*)d_ws;
  float* c0 = ws;
  float* c1 = c0 + (size_t)N * 128;
  unsigned short* tempb = (unsigned short*)(c1 + (size_t)N * 128);
  unsigned short* hb0   = tempb + (size_t)N * 384;
  unsigned short* xhb   = hb0 + (size_t)N * 128;
  int* indptr = (int*)(xhb + (size_t)N * 128);    // N+1
  int* fillc  = indptr + (N + 1);                 // N
  int* srcl   = fillc + N;                        // EP
  int* bsum   = srcl + EP;                        // ceil(N/1024)+pad
  size_t ip = (size_t)((bsum + 256) - (int*)ws);
  ip = (ip + 7) & ~(size_t)7;
  unsigned short* frags = (unsigned short*)((int*)ws + ip);
  unsigned short* WencF = frags;
  unsigned short* WgatF = WencF + 16384;
  unsigned short* W1F   = WgatF + 3 * 16384;
  unsigned short* L0F   = W1F + 3 * 8192;
  unsigned short* L1F   = L0F + 131072;

  float* regA = c1;
  float* aS   = c0;
  float* aD   = c0 + (size_t)N * 4;

  size_t need = ((size_t)N * 128 * 2) * 4 + (size_t)N * 384 * 2 + (size_t)N * 128 * 2 * 2
              + ((size_t)2 * N + 1 + EP + 264) * 4 + (size_t)(16384 * 4 + 8192 * 3 + 131072 * 2) * 2 + 64;
  if (ws_size < need) return;

  const int* esrc = ei;
  const int* edst = ei + E;
  const int rowTiles = (N + 63) / 64;
  const int nscan = (N + 1023) / 1024;

  // ---- build weight fragments ----
  build_frag_kmajor<<<64, 256, 0, stream>>>(Wenc, 128, WencF, 4, 8);
  for (int k = 0; k < 3; ++k) {
    build_frag_kmajor<<<64, 256, 0, stream>>>(Wgat + (size_t)k * 16384, 128, WgatF + (size_t)k * 16384, 4, 8);
    build_frag_kmajor<<<32, 256, 0, stream>>>(W1 + (size_t)k * 8192, 64, W1F + (size_t)k * 8192, 4, 4);
  }
  build_frag_lstm3<<<512, 256, 0, stream>>>(Wih0, Whh0, L0F);
  build_frag_lstm3<<<512, 256, 0, stream>>>(Wih1, Whh1, L1F);

  // ---- CSR by destination (self-loops appended), two-level scan ----
  hipMemsetAsync(fillc, 0, (size_t)N * sizeof(int), stream);
  count_kernel<<<(EP + 255) / 256, 256, 0, stream>>>(edst, fillc, E, EP);
  scan1_kernel<<<nscan, 1024, 0, stream>>>(fillc, indptr, bsum, N);
  scan2_kernel<<<1, 64, 0, stream>>>(bsum, indptr, nscan, N);
  scan3_kernel<<<nscan, 1024, 0, stream>>>(indptr, bsum, N);
  hipMemsetAsync(fillc, 0, (size_t)N * sizeof(int), stream);
  fill_kernel<<<(EP + 255) / 256, 256, 0, stream>>>(esrc, edst, indptr, fillc, srcl, E, EP);

  // ---- encoder ----
  gemm_mfma<8, 4, 0, 0, 0><<<dim3(rowTiles, 1), 256, 0, stream>>>(
      x, 128, WencF, 8, c0, nullptr, 128, nullptr, N);
  encoder_finish_kernel<<<(N * 128 + 255) / 256, 256, 0, stream>>>(c0, itype, mask, Wenc, benc, hb0, N);

  hipMemsetAsync(total, 0, sizeof(float), stream);

  const int waveGrid = (N * 64 + 255) / 256;

  // ---- 3 GAT hops + impact heads ----
  for (int k = 0; k < 3; ++k) {
    const unsigned short* hinb = (k == 0) ? hb0 : (tempb + (size_t)(k - 1) * 128);
    int ldin = (k == 0) ? 128 : 384;
    gemm_mfma<8, 4, 1, 0, 1><<<dim3(rowTiles, 1), 256, 0, stream>>>(
        hinb, ldin, WgatF + (size_t)k * 16384, 8, nullptr, xhb, 128, nullptr, N);
    gat_att_kernel<<<(N * 4 + 255) / 256, 256, 0, stream>>>(xhb, attS + k * 128, attD + k * 128, aS, aD, N);
    gat_fused_kernel<<<waveGrid, 256, 0, stream>>>(xhb, aS, aD, indptr, srcl, bgat + k * 128,
                                                   tempb + (size_t)k * 128, 384, N);
    gemm_mfma<4, 4, 0, 1, 1><<<dim3(rowTiles, 1), 256, 0, stream>>>(
        tempb + (size_t)k * 128, 384, W1F + (size_t)k * 8192, 4,
        regA, nullptr, 64, b1 + k * 64, N);
    float wk = ((k == 0) ? 1.f : (k == 1) ? 0.5f : 0.25f) / (3.0f * (float)N);
    impact_out_kernel<<<(N + 255) / 256, 256, 0, stream>>>(regA, W2 + k * 192, b2 + k * 3,
                                                           impacts + (size_t)k * N * 3, total, wk, N);
  }

  // ---- fully fused LSTM ----
  lstm_fused<<<rowTiles, 512, 0, stream>>>(tempb, L0F, L1F, bih0, bhh0, bih1, bhh1,
                                           temporal, hlast, N);
}